// Round 1
// baseline (899.203 us; speedup 1.0000x reference)
//
#include <hip/hip_runtime.h>
#include <math.h>

// Problem constants (B,S,D,H,HD) = (2,2048,1024,16,64)
#define CB 2
#define CS 2048
#define CD 1024
#define CH 16
#define CHD 64
#define CM (CB*CS)   // 4096 rows

// ---------------------------------------------------------------------------
// Kernel 1: QKV projection.  out = X @ W + b for W in {Wq,Wk,Wv}, written in
// [b,h,s,hd] layout (head-major) so attention reads are coalesced.
// Grid (M/64, D/64, 3), block 256.  64x64 tile, 4x4 per thread.
// A tile stored transposed (AsT[k][m], stride 68) -> both fragment reads are
// conflict-free ds_read_b128.
// ---------------------------------------------------------------------------
__global__ __launch_bounds__(256)
void qkv_gemm_kernel(const float* __restrict__ X,
                     const float* __restrict__ Wq, const float* __restrict__ bq,
                     const float* __restrict__ Wk, const float* __restrict__ bk,
                     const float* __restrict__ Wv, const float* __restrict__ bv,
                     float* __restrict__ Qo, float* __restrict__ Ko,
                     float* __restrict__ Vo)
{
    const float* W; const float* bias; float* out;
    if (blockIdx.z == 0)      { W = Wq; bias = bq; out = Qo; }
    else if (blockIdx.z == 1) { W = Wk; bias = bk; out = Ko; }
    else                      { W = Wv; bias = bv; out = Vo; }

    __shared__ float AsT[16][68];   // [k][m], padded stride 68 (16B-aligned rows)
    __shared__ float Bs[16][64];    // [k][n]

    const int row0 = blockIdx.x << 6;
    const int col0 = blockIdx.y << 6;
    const int tid  = threadIdx.x;
    const int tn   = tid & 15;      // output col group
    const int tm   = tid >> 4;      // output row group

    // loader assignments
    const int la_m = tid >> 2;          // 0..63   (row within A tile)
    const int la_k = (tid & 3) << 2;    // 0,4,8,12 (k chunk)
    const int lb_k = tid >> 4;          // 0..15
    const int lb_n = (tid & 15) << 2;   // 0..60

    float acc[4][4] = {{0.f,0.f,0.f,0.f},{0.f,0.f,0.f,0.f},
                       {0.f,0.f,0.f,0.f},{0.f,0.f,0.f,0.f}};

    const float* Xp = X + (size_t)(row0 + la_m) * CD + la_k;
    const float* Wp = W + (size_t)lb_k * CD + col0 + lb_n;

    for (int k0 = 0; k0 < CD; k0 += 16) {
        float4 av  = *(const float4*)(Xp + k0);
        float4 bv4 = *(const float4*)(Wp + (size_t)k0 * CD);
        __syncthreads();   // previous iteration's LDS reads done
        AsT[la_k + 0][la_m] = av.x;
        AsT[la_k + 1][la_m] = av.y;
        AsT[la_k + 2][la_m] = av.z;
        AsT[la_k + 3][la_m] = av.w;
        *(float4*)&Bs[lb_k][lb_n] = bv4;
        __syncthreads();
        #pragma unroll
        for (int k = 0; k < 16; ++k) {
            float4 a4 = *(const float4*)&AsT[k][tm << 2];
            float4 b4 = *(const float4*)&Bs[k][tn << 2];
            const float a[4] = {a4.x, a4.y, a4.z, a4.w};
            const float b[4] = {b4.x, b4.y, b4.z, b4.w};
            #pragma unroll
            for (int i = 0; i < 4; ++i)
                #pragma unroll
                for (int j = 0; j < 4; ++j)
                    acc[i][j] = fmaf(a[i], b[j], acc[i][j]);
        }
    }

    const int h = blockIdx.y;   // 64-col tile == one head
    float bb[4];
    #pragma unroll
    for (int j = 0; j < 4; ++j) bb[j] = bias[col0 + (tn << 2) + j];

    #pragma unroll
    for (int i = 0; i < 4; ++i) {
        int m     = row0 + (tm << 2) + i;
        int batch = m >> 11;          // / S
        int srow  = m & (CS - 1);     // % S
        float4 o4;
        o4.x = acc[i][0] + bb[0];
        o4.y = acc[i][1] + bb[1];
        o4.z = acc[i][2] + bb[2];
        o4.w = acc[i][3] + bb[3];
        *(float4*)(out + ((size_t)(batch * CH + h) * CS + srow) * CHD + (tn << 2)) = o4;
    }
}

// ---------------------------------------------------------------------------
// Kernel 2: flash-style attention, fp32, online softmax.
// Grid (S/64, B*H), block 256.  Per block: 64 q-rows x full HD=64.
// QsT/KsT stored [d][row] (stride 68) for conflict-free b128 fragment reads.
// P reuses K's LDS buffer (KsT dead after the scores matmul).
// Row state (m,l) kept in registers, replicated across the 16-lane row group
// via __shfl_xor butterflies (all lanes of a row group are in one wave).
// ---------------------------------------------------------------------------
__global__ __launch_bounds__(256)
void attn_kernel(const float* __restrict__ Q, const float* __restrict__ K,
                 const float* __restrict__ V, const float* __restrict__ mask,
                 float* __restrict__ out)
{
    __shared__ float QsT[64][68];   // [d][q]
    __shared__ float KP[64][68];    // KsT [d][k] during scores; PsT [k][q] during PV
    __shared__ float Vs[64][64];    // [k][dv]

    const int q0  = blockIdx.x << 6;
    const int bh  = blockIdx.y;
    const int b   = bh >> 4;        // / H
    const int h   = bh & 15;        // % H
    const int tid = threadIdx.x;
    const int tn  = tid & 15;
    const int tm  = tid >> 4;

    const float* Qb   = Q + (size_t)bh * CS * CHD;
    const float* Kb   = K + (size_t)bh * CS * CHD;
    const float* Vb   = V + (size_t)bh * CS * CHD;
    const float* mrow = mask + (size_t)b * CS;

    // ---- stage Q tile transposed (once per block) ----
    {
        const int r = tid >> 2;                    // 0..63
        #pragma unroll
        for (int it = 0; it < 4; ++it) {
            int d0 = ((tid & 3) << 2) + (it << 4); // 0..60
            float4 v = *(const float4*)(Qb + (size_t)(q0 + r) * CHD + d0);
            QsT[d0 + 0][r] = v.x;
            QsT[d0 + 1][r] = v.y;
            QsT[d0 + 2][r] = v.z;
            QsT[d0 + 3][r] = v.w;
        }
    }

    float m_i[4], l_i[4], o[4][4];
    #pragma unroll
    for (int i = 0; i < 4; ++i) {
        m_i[i] = -1e30f;
        l_i[i] = 0.f;
        #pragma unroll
        for (int j = 0; j < 4; ++j) o[i][j] = 0.f;
    }

    for (int kt = 0; kt < CS / 64; ++kt) {
        const int k0 = kt << 6;
        __syncthreads();   // prev iteration's PV reads (KP, Vs) done; also Q staging visible
        // ---- stage K (transposed) and V ----
        {
            const int r = tid >> 2;
            #pragma unroll
            for (int it = 0; it < 4; ++it) {
                int d0 = ((tid & 3) << 2) + (it << 4);
                float4 v = *(const float4*)(Kb + (size_t)(k0 + r) * CHD + d0);
                KP[d0 + 0][r] = v.x;
                KP[d0 + 1][r] = v.y;
                KP[d0 + 2][r] = v.z;
                KP[d0 + 3][r] = v.w;
            }
            const int rv = tid >> 4;
            const int dv = (tid & 15) << 2;
            #pragma unroll
            for (int it = 0; it < 4; ++it) {
                *(float4*)&Vs[rv + (it << 4)][dv] =
                    *(const float4*)(Vb + (size_t)(k0 + rv + (it << 4)) * CHD + dv);
            }
        }
        __syncthreads();

        // ---- S = Q K^T (per-thread 4x4) ----
        float s[4][4] = {{0.f,0.f,0.f,0.f},{0.f,0.f,0.f,0.f},
                         {0.f,0.f,0.f,0.f},{0.f,0.f,0.f,0.f}};
        for (int d = 0; d < 64; ++d) {
            float4 a4 = *(const float4*)&QsT[d][tm << 2];
            float4 b4 = *(const float4*)&KP[d][tn << 2];
            const float a[4] = {a4.x, a4.y, a4.z, a4.w};
            const float bq4[4] = {b4.x, b4.y, b4.z, b4.w};
            #pragma unroll
            for (int i = 0; i < 4; ++i)
                #pragma unroll
                for (int j = 0; j < 4; ++j)
                    s[i][j] = fmaf(a[i], bq4[j], s[i][j]);
        }

        // ---- scale + mask + online softmax ----
        float mk[4];
        #pragma unroll
        for (int j = 0; j < 4; ++j) mk[j] = mrow[k0 + (tn << 2) + j];

        float ps[4][4];
        #pragma unroll
        for (int i = 0; i < 4; ++i) {
            float sv[4];
            #pragma unroll
            for (int j = 0; j < 4; ++j) sv[j] = s[i][j] * 0.125f + mk[j];
            float mx = fmaxf(fmaxf(sv[0], sv[1]), fmaxf(sv[2], sv[3]));
            mx = fmaxf(mx, __shfl_xor(mx, 1));
            mx = fmaxf(mx, __shfl_xor(mx, 2));
            mx = fmaxf(mx, __shfl_xor(mx, 4));
            mx = fmaxf(mx, __shfl_xor(mx, 8));
            float mnew  = fmaxf(m_i[i], mx);
            float alpha = __expf(m_i[i] - mnew);
            m_i[i] = mnew;
            float rs = 0.f;
            #pragma unroll
            for (int j = 0; j < 4; ++j) {
                ps[i][j] = __expf(sv[j] - mnew);
                rs += ps[i][j];
            }
            rs += __shfl_xor(rs, 1);
            rs += __shfl_xor(rs, 2);
            rs += __shfl_xor(rs, 4);
            rs += __shfl_xor(rs, 8);
            l_i[i] = l_i[i] * alpha + rs;
            #pragma unroll
            for (int j = 0; j < 4; ++j) o[i][j] *= alpha;
        }

        __syncthreads();   // all scores reads of KP done -> safe to overwrite with P
        #pragma unroll
        for (int i = 0; i < 4; ++i)
            #pragma unroll
            for (int j = 0; j < 4; ++j)
                KP[(tn << 2) + j][(tm << 2) + i] = ps[i][j];   // PsT[k][q]
        __syncthreads();

        // ---- O += P V ----
        for (int k = 0; k < 64; ++k) {
            float4 a4 = *(const float4*)&KP[k][tm << 2];
            float4 b4 = *(const float4*)&Vs[k][tn << 2];
            const float a[4] = {a4.x, a4.y, a4.z, a4.w};
            const float bv4[4] = {b4.x, b4.y, b4.z, b4.w};
            #pragma unroll
            for (int i = 0; i < 4; ++i)
                #pragma unroll
                for (int j = 0; j < 4; ++j)
                    o[i][j] = fmaf(a[i], bv4[j], o[i][j]);
        }
    }

    // ---- epilogue: normalize and store [B,S,D] ----
    #pragma unroll
    for (int i = 0; i < 4; ++i) {
        float inv  = 1.0f / l_i[i];
        int   srow = q0 + (tm << 2) + i;
        float4 o4;
        o4.x = o[i][0] * inv;
        o4.y = o[i][1] * inv;
        o4.z = o[i][2] * inv;
        o4.w = o[i][3] * inv;
        *(float4*)(out + ((size_t)(b * CS + srow)) * CD + h * CHD + (tn << 2)) = o4;
    }
}

// ---------------------------------------------------------------------------
extern "C" void kernel_launch(void* const* d_in, const int* in_sizes, int n_in,
                              void* d_out, int out_size, void* d_ws, size_t ws_size,
                              hipStream_t stream)
{
    const float* X    = (const float*)d_in[0];
    const float* mask = (const float*)d_in[1];
    const float* Wq   = (const float*)d_in[2];
    const float* bq   = (const float*)d_in[3];
    const float* Wk   = (const float*)d_in[4];
    const float* bk   = (const float*)d_in[5];
    const float* Wv   = (const float*)d_in[6];
    const float* bv   = (const float*)d_in[7];
    float* out = (float*)d_out;

    const size_t per = (size_t)CB * CH * CS * CHD;   // 4,194,304 floats = 16 MB
    float* Qb = (float*)d_ws;
    float* Kb = Qb + per;
    float* Vb = Kb + per;

    dim3 g1(CM / 64, CD / 64, 3);
    qkv_gemm_kernel<<<g1, 256, 0, stream>>>(X, Wq, bq, Wk, bk, Wv, bv, Qb, Kb, Vb);

    dim3 g2(CS / 64, CB * CH);
    attn_kernel<<<g2, 256, 0, stream>>>(Qb, Kb, Vb, mask, out);
}

// Round 2
// 254.447 us; speedup vs baseline: 3.5340x; 3.5340x over previous
//
#include <hip/hip_runtime.h>
#include <math.h>

// Problem constants (B,S,D,H,HD) = (2,2048,1024,16,64)
#define CB 2
#define CS 2048
#define CD 1024
#define CH 16
#define CHD 64
#define CM (CB*CS)   // 4096 rows

typedef unsigned short u16;
using bf16x8 = __attribute__((ext_vector_type(8))) short;          // 8 bf16 (4 VGPRs)
using u16x8  = __attribute__((ext_vector_type(8))) unsigned short;
using f32x4  = __attribute__((ext_vector_type(4))) float;

// RNE float -> bf16 bit pattern
__device__ __forceinline__ u16 f2bf(float f) {
    unsigned int u = __float_as_uint(f);
    u = (u + 0x7FFFu + ((u >> 16) & 1u)) >> 16;
    return (u16)u;
}

// ---------------------------------------------------------------------------
// X [4096,1024] fp32 -> bf16 (same layout).  8 elems/thread.
// ---------------------------------------------------------------------------
__global__ __launch_bounds__(256)
void convert_x(const float* __restrict__ X, u16* __restrict__ Xb)
{
    size_t i = ((size_t)blockIdx.x * 256 + threadIdx.x) * 8;
    float4 v0 = *(const float4*)(X + i);
    float4 v1 = *(const float4*)(X + i + 4);
    u16x8 o;
    o[0] = f2bf(v0.x); o[1] = f2bf(v0.y); o[2] = f2bf(v0.z); o[3] = f2bf(v0.w);
    o[4] = f2bf(v1.x); o[5] = f2bf(v1.y); o[6] = f2bf(v1.z); o[7] = f2bf(v1.w);
    *(u16x8*)(Xb + i) = o;
}

// ---------------------------------------------------------------------------
// W [K=1024][N=1024] fp32 -> Wt [N][K] bf16 (transposed), 3 matrices (z).
// 64x64 tile via LDS.
// ---------------------------------------------------------------------------
__global__ __launch_bounds__(256)
void convert_wt(const float* __restrict__ Wq, const float* __restrict__ Wk,
                const float* __restrict__ Wv, u16* __restrict__ Wt)
{
    const int z = blockIdx.z;
    const float* W = (z == 0) ? Wq : (z == 1) ? Wk : Wv;
    u16* Wo = Wt + (size_t)z * CD * CD;

    __shared__ u16 T[64][72];   // [n][k], pad 64->72 (stride 144B = 9x16B)
    const int k0 = blockIdx.x << 6;
    const int n0 = blockIdx.y << 6;
    const int tid = threadIdx.x;

    #pragma unroll
    for (int it = 0; it < 4; ++it) {
        int r = (tid >> 4) + (it << 4);       // k row 0..63
        int c = (tid & 15) << 2;              // n col 0..60
        float4 v = *(const float4*)(W + (size_t)(k0 + r) * CD + n0 + c);
        T[c + 0][r] = f2bf(v.x);
        T[c + 1][r] = f2bf(v.y);
        T[c + 2][r] = f2bf(v.z);
        T[c + 3][r] = f2bf(v.w);
    }
    __syncthreads();
    #pragma unroll
    for (int it = 0; it < 2; ++it) {
        int cc = tid + (it << 8);
        int n  = cc >> 3;
        int ch = (cc & 7) << 3;
        *(uint4*)(Wo + (size_t)(n0 + n) * CD + k0 + ch) = *(const uint4*)&T[n][ch];
    }
}

// ---------------------------------------------------------------------------
// QKV GEMM, bf16 MFMA 16x16x32.  C = Xb @ Wt^T + bias.
// 128x128 tile, BK=32, 256 threads = 4 waves (2x2), 4x4 MFMA tiles/wave.
// z=0/1 -> Q/K written bf16 [b,h,s,hd]; z=2 -> V written bf16 TRANSPOSED
// [b,h,hd,s] via LDS half-tile transpose (PV B-fragments need k-contiguous V^T).
// ---------------------------------------------------------------------------
__global__ __launch_bounds__(256, 3)
void qkv_gemm_mfma(const u16* __restrict__ Xb, const u16* __restrict__ Wt,
                   const float* __restrict__ bq, const float* __restrict__ bk,
                   const float* __restrict__ bv,
                   u16* __restrict__ Qb, u16* __restrict__ Kb,
                   u16* __restrict__ Vt)
{
    const int z = blockIdx.z;
    const u16* W = Wt + (size_t)z * CD * CD;
    const float* bias = (z == 0) ? bq : (z == 1) ? bk : bv;

    __shared__ u16 smem[10240];
    u16 (*As)[40] = (u16(*)[40])smem;           // [m][k], pad 32->40 (80B rows)
    u16 (*Bs)[40] = (u16(*)[40])(smem + 5120);  // [n][k]

    const int tid  = threadIdx.x;
    const int w    = tid >> 6;
    const int l    = tid & 63;
    const int l15  = l & 15;
    const int quad = l >> 4;
    const int wm   = w >> 1;
    const int wn   = w & 1;

    const int row0 = blockIdx.x << 7;
    const int n0   = blockIdx.y << 7;

    f32x4 acc[4][4];
    #pragma unroll
    for (int mi = 0; mi < 4; ++mi)
        #pragma unroll
        for (int nt = 0; nt < 4; ++nt)
            acc[mi][nt] = (f32x4){0.f, 0.f, 0.f, 0.f};

    const int sr = tid >> 2;           // 0..63 (row; +64 for second chunk)
    const int sk = (tid & 3) << 3;     // 0,8,16,24

    const u16* Ap = Xb + (size_t)row0 * CD;
    const u16* Bp = W  + (size_t)n0   * CD;

    for (int k0 = 0; k0 < CD; k0 += 32) {
        uint4 a0 = *(const uint4*)(Ap + (size_t)sr        * CD + k0 + sk);
        uint4 a1 = *(const uint4*)(Ap + (size_t)(sr + 64) * CD + k0 + sk);
        uint4 b0 = *(const uint4*)(Bp + (size_t)sr        * CD + k0 + sk);
        uint4 b1 = *(const uint4*)(Bp + (size_t)(sr + 64) * CD + k0 + sk);
        __syncthreads();
        *(uint4*)&As[sr     ][sk] = a0;
        *(uint4*)&As[sr + 64][sk] = a1;
        *(uint4*)&Bs[sr     ][sk] = b0;
        *(uint4*)&Bs[sr + 64][sk] = b1;
        __syncthreads();

        bf16x8 af[4], bfr[4];
        #pragma unroll
        for (int mi = 0; mi < 4; ++mi)
            af[mi] = *(const bf16x8*)&As[wm * 64 + mi * 16 + l15][quad * 8];
        #pragma unroll
        for (int nt = 0; nt < 4; ++nt)
            bfr[nt] = *(const bf16x8*)&Bs[wn * 64 + nt * 16 + l15][quad * 8];
        #pragma unroll
        for (int mi = 0; mi < 4; ++mi)
            #pragma unroll
            for (int nt = 0; nt < 4; ++nt)
                acc[mi][nt] = __builtin_amdgcn_mfma_f32_16x16x32_bf16(
                    af[mi], bfr[nt], acc[mi][nt], 0, 0, 0);
    }

    if (z < 2) {
        u16* Og = (z == 0) ? Qb : Kb;
        #pragma unroll
        for (int nt = 0; nt < 4; ++nt) {
            int col = n0 + wn * 64 + nt * 16 + l15;
            float bb = bias[col];
            int h  = col >> 6;
            int hd = col & 63;
            #pragma unroll
            for (int mi = 0; mi < 4; ++mi)
                #pragma unroll
                for (int r = 0; r < 4; ++r) {
                    int m = row0 + wm * 64 + mi * 16 + quad * 4 + r;
                    int b = m >> 11;
                    int s = m & (CS - 1);
                    Og[(((size_t)(b * CH + h)) * CS + s) * CHD + hd] =
                        f2bf(acc[mi][nt][r] + bb);
                }
        }
    } else {
        // V: transpose 128x128 tile via LDS halves -> [b,h,hd,s]
        __syncthreads();   // K-loop LDS reads done
        u16 (*Ct)[136] = (u16(*)[136])smem;   // [n_half][m], stride 272B = 17x16B
        #pragma unroll
        for (int nh = 0; nh < 2; ++nh) {
            if (wn == nh) {
                #pragma unroll
                for (int nt = 0; nt < 4; ++nt) {
                    int col = n0 + nh * 64 + nt * 16 + l15;
                    float bb = bias[col];
                    #pragma unroll
                    for (int mi = 0; mi < 4; ++mi)
                        #pragma unroll
                        for (int r = 0; r < 4; ++r) {
                            int ml = wm * 64 + mi * 16 + quad * 4 + r;
                            Ct[nt * 16 + l15][ml] = f2bf(acc[mi][nt][r] + bb);
                        }
                }
            }
            __syncthreads();
            #pragma unroll
            for (int it = 0; it < 4; ++it) {
                int c   = tid + (it << 8);
                int dvl = c >> 4;          // 0..63
                int ch  = c & 15;          // 0..15 -> m chunk of 8
                uint4 vdat = *(const uint4*)&Ct[dvl][ch * 8];
                int col = n0 + nh * 64 + dvl;
                int h   = col >> 6;
                int dv  = col & 63;
                int m0  = row0 + ch * 8;
                int b   = m0 >> 11;
                int s0  = m0 & (CS - 1);
                *(uint4*)(Vt + (((size_t)(b * CH + h)) * CHD + dv) * CS + s0) = vdat;
            }
            __syncthreads();
        }
    }
}

// ---------------------------------------------------------------------------
// Flash attention, bf16 MFMA.  Grid (S/64, B*H), block 256 (4 waves).
// Wave w owns q rows [w*16, w*16+16).  k-tile 64.  Online softmax in C-layout
// registers; P round-trips through K's LDS buffer in A-layout bf16.
// ---------------------------------------------------------------------------
__global__ __launch_bounds__(256, 4)
void attn_mfma(const u16* __restrict__ Qg, const u16* __restrict__ Kg,
               const u16* __restrict__ Vtg, const float* __restrict__ mask,
               float* __restrict__ out)
{
    __shared__ u16 Qs[64][72];    // [q][d]
    __shared__ u16 KPs[64][72];   // K [k][d] during scores; P [q][k] during PV
    __shared__ u16 Vts[64][72];   // V^T [dv][k]

    const int q0  = blockIdx.x << 6;
    const int bh  = blockIdx.y;
    const int b   = bh >> 4;
    const int h   = bh & 15;
    const int tid = threadIdx.x;
    const int w    = tid >> 6;
    const int l    = tid & 63;
    const int l15  = l & 15;
    const int quad = l >> 4;

    const u16* Qp = Qg  + (size_t)bh * CS * CHD;
    const u16* Kp = Kg  + (size_t)bh * CS * CHD;
    const u16* Vp = Vtg + (size_t)bh * CHD * CS;
    const float* mrow = mask + (size_t)b * CS;

    // stage Q tile (64 rows x 64 bf16)
    #pragma unroll
    for (int it = 0; it < 2; ++it) {
        int c = tid + (it << 8);
        int row = c >> 3, ch = (c & 7) << 3;
        *(uint4*)&Qs[row][ch] = *(const uint4*)(Qp + (size_t)(q0 + row) * CHD + ch);
    }

    float m_i[4], l_i[4];
    f32x4 O[4];
    #pragma unroll
    for (int r = 0; r < 4; ++r) { m_i[r] = -1e30f; l_i[r] = 0.f; }
    #pragma unroll
    for (int dt = 0; dt < 4; ++dt) O[dt] = (f32x4){0.f, 0.f, 0.f, 0.f};

    for (int kt = 0; kt < CS / 64; ++kt) {
        const int k0 = kt << 6;
        __syncthreads();   // prev PV reads done (also covers Q staging on iter 0)
        #pragma unroll
        for (int it = 0; it < 2; ++it) {
            int c = tid + (it << 8);
            int row = c >> 3, ch = (c & 7) << 3;
            *(uint4*)&KPs[row][ch] = *(const uint4*)(Kp + (size_t)(k0 + row) * CHD + ch);
            *(uint4*)&Vts[row][ch] = *(const uint4*)(Vp + (size_t)row * CS + k0 + ch);
        }
        __syncthreads();

        // ---- S = Q K^T ----
        bf16x8 a0 = *(const bf16x8*)&Qs[w * 16 + l15][quad * 8];
        bf16x8 a1 = *(const bf16x8*)&Qs[w * 16 + l15][32 + quad * 8];
        f32x4 sc[4];
        #pragma unroll
        for (int nt = 0; nt < 4; ++nt) {
            bf16x8 b0 = *(const bf16x8*)&KPs[nt * 16 + l15][quad * 8];
            bf16x8 b1 = *(const bf16x8*)&KPs[nt * 16 + l15][32 + quad * 8];
            sc[nt] = (f32x4){0.f, 0.f, 0.f, 0.f};
            sc[nt] = __builtin_amdgcn_mfma_f32_16x16x32_bf16(a0, b0, sc[nt], 0, 0, 0);
            sc[nt] = __builtin_amdgcn_mfma_f32_16x16x32_bf16(a1, b1, sc[nt], 0, 0, 0);
        }

        // ---- online softmax (C-layout: col = l15 per nt, row = quad*4+r) ----
        float mk[4];
        #pragma unroll
        for (int nt = 0; nt < 4; ++nt) mk[nt] = mrow[k0 + nt * 16 + l15];

        u16 pb[4][4];
        #pragma unroll
        for (int r = 0; r < 4; ++r) {
            float sv0 = sc[0][r] * 0.125f + mk[0];
            float sv1 = sc[1][r] * 0.125f + mk[1];
            float sv2 = sc[2][r] * 0.125f + mk[2];
            float sv3 = sc[3][r] * 0.125f + mk[3];
            float mx = fmaxf(fmaxf(sv0, sv1), fmaxf(sv2, sv3));
            mx = fmaxf(mx, __shfl_xor(mx, 1));
            mx = fmaxf(mx, __shfl_xor(mx, 2));
            mx = fmaxf(mx, __shfl_xor(mx, 4));
            mx = fmaxf(mx, __shfl_xor(mx, 8));
            float mnew  = fmaxf(m_i[r], mx);
            float alpha = __expf(m_i[r] - mnew);
            m_i[r] = mnew;
            float p0 = __expf(sv0 - mnew);
            float p1 = __expf(sv1 - mnew);
            float p2 = __expf(sv2 - mnew);
            float p3 = __expf(sv3 - mnew);
            float rs = (p0 + p1) + (p2 + p3);
            rs += __shfl_xor(rs, 1);
            rs += __shfl_xor(rs, 2);
            rs += __shfl_xor(rs, 4);
            rs += __shfl_xor(rs, 8);
            l_i[r] = l_i[r] * alpha + rs;
            pb[0][r] = f2bf(p0);
            pb[1][r] = f2bf(p1);
            pb[2][r] = f2bf(p2);
            pb[3][r] = f2bf(p3);
            O[0][r] *= alpha; O[1][r] *= alpha; O[2][r] *= alpha; O[3][r] *= alpha;
        }

        __syncthreads();   // all K reads done -> overwrite with P (A-layout [q][k])
        #pragma unroll
        for (int nt = 0; nt < 4; ++nt)
            #pragma unroll
            for (int r = 0; r < 4; ++r)
                KPs[w * 16 + quad * 4 + r][nt * 16 + l15] = pb[nt][r];
        __syncthreads();

        // ---- O += P V ----
        bf16x8 p0f = *(const bf16x8*)&KPs[w * 16 + l15][quad * 8];
        bf16x8 p1f = *(const bf16x8*)&KPs[w * 16 + l15][32 + quad * 8];
        #pragma unroll
        for (int dt = 0; dt < 4; ++dt) {
            bf16x8 v0 = *(const bf16x8*)&Vts[dt * 16 + l15][quad * 8];
            bf16x8 v1 = *(const bf16x8*)&Vts[dt * 16 + l15][32 + quad * 8];
            O[dt] = __builtin_amdgcn_mfma_f32_16x16x32_bf16(p0f, v0, O[dt], 0, 0, 0);
            O[dt] = __builtin_amdgcn_mfma_f32_16x16x32_bf16(p1f, v1, O[dt], 0, 0, 0);
        }
    }

    // ---- epilogue: normalize, store fp32 [B,S,D] ----
    #pragma unroll
    for (int r = 0; r < 4; ++r) {
        float inv = 1.0f / l_i[r];
        int s_row = q0 + w * 16 + quad * 4 + r;
        float* orow = out + ((size_t)b * CS + s_row) * CD + h * CHD;
        #pragma unroll
        for (int dt = 0; dt < 4; ++dt)
            orow[dt * 16 + l15] = O[dt][r] * inv;
    }
}

// ---------------------------------------------------------------------------
extern "C" void kernel_launch(void* const* d_in, const int* in_sizes, int n_in,
                              void* d_out, int out_size, void* d_ws, size_t ws_size,
                              hipStream_t stream)
{
    const float* X    = (const float*)d_in[0];
    const float* mask = (const float*)d_in[1];
    const float* Wq   = (const float*)d_in[2];
    const float* bq   = (const float*)d_in[3];
    const float* Wk   = (const float*)d_in[4];
    const float* bk   = (const float*)d_in[5];
    const float* Wv   = (const float*)d_in[6];
    const float* bv   = (const float*)d_in[7];
    float* out = (float*)d_out;

    char* ws = (char*)d_ws;
    u16* Xb = (u16*)(ws);                        // 8 MB
    u16* Wt = (u16*)(ws + ((size_t)8  << 20));   // 6 MB (3 x 2MB)
    u16* Qb = (u16*)(ws + ((size_t)14 << 20));   // 8 MB
    u16* Kb = (u16*)(ws + ((size_t)22 << 20));   // 8 MB
    u16* Vt = (u16*)(ws + ((size_t)30 << 20));   // 8 MB

    convert_x<<<CM * CD / (256 * 8), 256, 0, stream>>>(X, Xb);
    convert_wt<<<dim3(16, 16, 3), 256, 0, stream>>>(Wq, Wk, Wv, Wt);
    qkv_gemm_mfma<<<dim3(CM / 128, CD / 128, 3), 256, 0, stream>>>(
        Xb, Wt, bq, bk, bv, Qb, Kb, Vt);
    attn_mfma<<<dim3(CS / 64, CB * CH), 256, 0, stream>>>(Qb, Kb, Vt, mask, out);
}

// Round 3
// 238.600 us; speedup vs baseline: 3.7687x; 1.0664x over previous
//
#include <hip/hip_runtime.h>
#include <math.h>

// Problem constants (B,S,D,H,HD) = (2,2048,1024,16,64)
#define CB 2
#define CS 2048
#define CD 1024
#define CH 16
#define CHD 64
#define CM (CB*CS)   // 4096 rows

typedef unsigned short u16;
using bf16x8 = __attribute__((ext_vector_type(8))) short;          // 8 bf16 (4 VGPRs)
using u16x8  = __attribute__((ext_vector_type(8))) unsigned short;
using f32x4  = __attribute__((ext_vector_type(4))) float;

// RNE float -> bf16 bit pattern
__device__ __forceinline__ u16 f2bf(float f) {
    unsigned int u = __float_as_uint(f);
    u = (u + 0x7FFFu + ((u >> 16) & 1u)) >> 16;
    return (u16)u;
}

// cheap round-half-up pack of two fp32 -> packed bf16x2 (for P in [0,1]; <=0.5ulp)
__device__ __forceinline__ unsigned pack2bf(float a, float b) {
    unsigned ua = (__float_as_uint(a) + 0x8000u) >> 16;
    unsigned ub = (__float_as_uint(b) + 0x8000u) & 0xFFFF0000u;
    return ua | ub;
}

// async global->LDS, 16B per lane; LDS dest = wave-uniform base + lane*16
__device__ __forceinline__ void load_lds16(const u16* g, u16* l) {
    __builtin_amdgcn_global_load_lds(
        (const __attribute__((address_space(1))) unsigned int*)g,
        (__attribute__((address_space(3))) unsigned int*)l, 16, 0, 0);
}

// ---------------------------------------------------------------------------
// X [4096,1024] fp32 -> bf16 (same layout).  8 elems/thread.
// ---------------------------------------------------------------------------
__global__ __launch_bounds__(256)
void convert_x(const float* __restrict__ X, u16* __restrict__ Xb)
{
    size_t i = ((size_t)blockIdx.x * 256 + threadIdx.x) * 8;
    float4 v0 = *(const float4*)(X + i);
    float4 v1 = *(const float4*)(X + i + 4);
    u16x8 o;
    o[0] = f2bf(v0.x); o[1] = f2bf(v0.y); o[2] = f2bf(v0.z); o[3] = f2bf(v0.w);
    o[4] = f2bf(v1.x); o[5] = f2bf(v1.y); o[6] = f2bf(v1.z); o[7] = f2bf(v1.w);
    *(u16x8*)(Xb + i) = o;
}

// ---------------------------------------------------------------------------
// W [K][N] fp32 -> Wt [N][K] bf16 (transposed), 3 matrices (z).
// ---------------------------------------------------------------------------
__global__ __launch_bounds__(256)
void convert_wt(const float* __restrict__ Wq, const float* __restrict__ Wk,
                const float* __restrict__ Wv, u16* __restrict__ Wt)
{
    const int z = blockIdx.z;
    const float* W = (z == 0) ? Wq : (z == 1) ? Wk : Wv;
    u16* Wo = Wt + (size_t)z * CD * CD;

    __shared__ u16 T[64][72];
    const int k0 = blockIdx.x << 6;
    const int n0 = blockIdx.y << 6;
    const int tid = threadIdx.x;

    #pragma unroll
    for (int it = 0; it < 4; ++it) {
        int r = (tid >> 4) + (it << 4);
        int c = (tid & 15) << 2;
        float4 v = *(const float4*)(W + (size_t)(k0 + r) * CD + n0 + c);
        T[c + 0][r] = f2bf(v.x);
        T[c + 1][r] = f2bf(v.y);
        T[c + 2][r] = f2bf(v.z);
        T[c + 3][r] = f2bf(v.w);
    }
    __syncthreads();
    #pragma unroll
    for (int it = 0; it < 2; ++it) {
        int cc = tid + (it << 8);
        int n  = cc >> 3;
        int ch = (cc & 7) << 3;
        *(uint4*)(Wo + (size_t)(n0 + n) * CD + k0 + ch) = *(const uint4*)&T[n][ch];
    }
}

// ---------------------------------------------------------------------------
// QKV GEMM, bf16 MFMA 16x16x32, m97 structure: 128x128 tile, BK=32,
// global_load_lds width-16 staging into UNPADDED As/Bs [128][32] (lane-order
// contiguity required by the instruction).  4 waves, 64x64 wave-tile.
// z=0/1 -> Q/K bf16 [b,h,s,hd]; z=2 -> V bf16 transposed [b,h,hd,s].
// ---------------------------------------------------------------------------
__global__ __launch_bounds__(256, 3)
void qkv_gemm_mfma(const u16* __restrict__ Xb, const u16* __restrict__ Wt,
                   const float* __restrict__ bq, const float* __restrict__ bk,
                   const float* __restrict__ bv,
                   u16* __restrict__ Qb, u16* __restrict__ Kb,
                   u16* __restrict__ Vt)
{
    const int z = blockIdx.z;
    const u16* W = Wt + (size_t)z * CD * CD;
    const float* bias = (z == 0) ? bq : (z == 1) ? bk : bv;

    __shared__ u16 smem[8704];          // As 4096 + Bs 4096; epilogue Ct 8704
    u16* As = smem;                     // [128][32] row-major, no pad
    u16* Bs = smem + 4096;              // [128][32]

    const int tid  = threadIdx.x;
    const int w    = tid >> 6;
    const int l    = tid & 63;
    const int l15  = l & 15;
    const int quad = l >> 4;
    const int wm   = w >> 1;
    const int wn   = w & 1;

    const int row0 = blockIdx.x << 7;
    const int n0   = blockIdx.y << 7;

    f32x4 acc[4][4];
    #pragma unroll
    for (int mi = 0; mi < 4; ++mi)
        #pragma unroll
        for (int nt = 0; nt < 4; ++nt)
            acc[mi][nt] = (f32x4){0.f, 0.f, 0.f, 0.f};

    const u16* Ag = Xb + (size_t)row0 * CD;
    const u16* Bg = W  + (size_t)n0   * CD;
    const int lr = l >> 2;          // 0..15: row within 16-row chunk
    const int lc = (l & 3) << 3;    // 0,8,16,24 u16: 16B column chunk

    for (int k0 = 0; k0 < CD; k0 += 32) {
        __syncthreads();   // previous iteration's fragment reads done
        #pragma unroll
        for (int i = 0; i < 2; ++i) {
            int c = w * 2 + i;      // 0..7: 16-row chunk id
            load_lds16(Ag + (size_t)(c * 16 + lr) * CD + k0 + lc, As + c * 512);
            load_lds16(Bg + (size_t)(c * 16 + lr) * CD + k0 + lc, Bs + c * 512);
        }
        __syncthreads();   // drains vmcnt (global_load_lds) before ds_read

        bf16x8 af[4], bfr[4];
        #pragma unroll
        for (int mi = 0; mi < 4; ++mi)
            af[mi] = *(const bf16x8*)&As[(wm * 64 + mi * 16 + l15) * 32 + quad * 8];
        #pragma unroll
        for (int nt = 0; nt < 4; ++nt)
            bfr[nt] = *(const bf16x8*)&Bs[(wn * 64 + nt * 16 + l15) * 32 + quad * 8];
        #pragma unroll
        for (int mi = 0; mi < 4; ++mi)
            #pragma unroll
            for (int nt = 0; nt < 4; ++nt)
                acc[mi][nt] = __builtin_amdgcn_mfma_f32_16x16x32_bf16(
                    af[mi], bfr[nt], acc[mi][nt], 0, 0, 0);
    }

    if (z < 2) {
        u16* Og = (z == 0) ? Qb : Kb;
        #pragma unroll
        for (int nt = 0; nt < 4; ++nt) {
            int col = n0 + wn * 64 + nt * 16 + l15;
            float bb = bias[col];
            int h  = col >> 6;
            int hd = col & 63;
            #pragma unroll
            for (int mi = 0; mi < 4; ++mi)
                #pragma unroll
                for (int r = 0; r < 4; ++r) {
                    int m = row0 + wm * 64 + mi * 16 + quad * 4 + r;
                    int b = m >> 11;
                    int s = m & (CS - 1);
                    Og[(((size_t)(b * CH + h)) * CS + s) * CHD + hd] =
                        f2bf(acc[mi][nt][r] + bb);
                }
        }
    } else {
        // V: transpose 128x128 tile via LDS halves -> [b,h,hd,s]
        __syncthreads();   // K-loop LDS reads done
        u16 (*Ct)[136] = (u16(*)[136])smem;   // 64x136 = 8704 u16
        #pragma unroll
        for (int nh = 0; nh < 2; ++nh) {
            if (wn == nh) {
                #pragma unroll
                for (int nt = 0; nt < 4; ++nt) {
                    int col = n0 + nh * 64 + nt * 16 + l15;
                    float bb = bias[col];
                    #pragma unroll
                    for (int mi = 0; mi < 4; ++mi)
                        #pragma unroll
                        for (int r = 0; r < 4; ++r) {
                            int ml = wm * 64 + mi * 16 + quad * 4 + r;
                            Ct[nt * 16 + l15][ml] = f2bf(acc[mi][nt][r] + bb);
                        }
                }
            }
            __syncthreads();
            #pragma unroll
            for (int it = 0; it < 4; ++it) {
                int c   = tid + (it << 8);
                int dvl = c >> 4;
                int ch  = c & 15;
                uint4 vdat = *(const uint4*)&Ct[dvl][ch * 8];
                int col = n0 + nh * 64 + dvl;
                int h   = col >> 6;
                int dv  = col & 63;
                int m0  = row0 + ch * 8;
                int b   = m0 >> 11;
                int s0  = m0 & (CS - 1);
                *(uint4*)(Vt + (((size_t)(b * CH + h)) * CHD + dv) * CS + s0) = vdat;
            }
            __syncthreads();
        }
    }
}

// ---------------------------------------------------------------------------
// Flash attention v2: S^T = K.Q^T trick, barrier-free K-loop.
// Grid (S/128, B*H), block 256 = 4 waves; wave owns 32 q (2 n-tiles).
// K/V/Q fragments read directly from global (layouts verified in round 2);
// P goes through per-wave-private XOR-swizzled LDS (no __syncthreads).
// Softmax per q lives at lane l15 (C-layout col of S^T): 2 butterflies total.
// ---------------------------------------------------------------------------
__global__ __launch_bounds__(256, 2)
void attn_mfma(const u16* __restrict__ Qg, const u16* __restrict__ Kg,
               const u16* __restrict__ Vtg, const float* __restrict__ mask,
               float* __restrict__ out)
{
    __shared__ float msk[CS];           // 8 KB: mask row (whole S)
    __shared__ u16   Pl[4][32 * 64];    // 16 KB: per-wave P buffers

    const int q0  = blockIdx.x << 7;
    const int bh  = blockIdx.y;
    const int b   = bh >> 4;
    const int h   = bh & 15;
    const int tid = threadIdx.x;
    const int w    = tid >> 6;
    const int l    = tid & 63;
    const int l15  = l & 15;
    const int quad = l >> 4;
    const int q7   = l15 & 7;           // XOR-swizzle key (qrow & 7 == l15 & 7)

    const u16* Qp = Qg  + (size_t)bh * CS * CHD;
    const u16* Kp = Kg  + (size_t)bh * CS * CHD;
    const u16* Vp = Vtg + (size_t)bh * CHD * CS;
    const float* mrow = mask + (size_t)b * CS;

    // stage mask row once (only barrier in the kernel)
    {
        int i = tid * 8;
        float4 a = *(const float4*)(mrow + i);
        float4 c = *(const float4*)(mrow + i + 4);
        msk[i + 0] = a.x; msk[i + 1] = a.y; msk[i + 2] = a.z; msk[i + 3] = a.w;
        msk[i + 4] = c.x; msk[i + 5] = c.y; msk[i + 6] = c.z; msk[i + 7] = c.w;
    }
    __syncthreads();

    u16* Pw = &Pl[w][0];

    // Q B-fragments cached in registers for the whole k-loop:
    // B[n=q][k=d]: n = l15 -> q = q0+32w+16nq+l15, k = hh*32 + quad*8 + j
    bf16x8 qf[2][2];
    #pragma unroll
    for (int nq = 0; nq < 2; ++nq)
        #pragma unroll
        for (int hh = 0; hh < 2; ++hh)
            qf[nq][hh] = *(const bf16x8*)(
                Qp + (size_t)(q0 + w * 32 + nq * 16 + l15) * CHD + hh * 32 + quad * 8);

    float mst[2] = {-3.0e38f, -3.0e38f};
    float lst[2] = {0.f, 0.f};
    f32x4 O[2][4];
    #pragma unroll
    for (int nq = 0; nq < 2; ++nq)
        #pragma unroll
        for (int dt = 0; dt < 4; ++dt)
            O[nq][dt] = (f32x4){0.f, 0.f, 0.f, 0.f};

    for (int k0 = 0; k0 < CS; k0 += 64) {
        // ---- K A-fragments direct from global: A[m=key][k=d] ----
        bf16x8 kf[4][2];
        #pragma unroll
        for (int mt = 0; mt < 4; ++mt)
            #pragma unroll
            for (int hh = 0; hh < 2; ++hh)
                kf[mt][hh] = *(const bf16x8*)(
                    Kp + (size_t)(k0 + mt * 16 + l15) * CHD + hh * 32 + quad * 8);

        // mask values: element r <-> key k0+16mt+4quad+r (matches C-row layout)
        f32x4 mkv[4];
        #pragma unroll
        for (int mt = 0; mt < 4; ++mt)
            mkv[mt] = *(const f32x4*)&msk[k0 + mt * 16 + quad * 4];

        // ---- S^T = K.Q^T: C col = q (l15), row = key-local (quad*4+r) ----
        f32x4 st[2][4];
        #pragma unroll
        for (int nq = 0; nq < 2; ++nq)
            #pragma unroll
            for (int mt = 0; mt < 4; ++mt) {
                f32x4 v = (f32x4){0.f, 0.f, 0.f, 0.f};
                v = __builtin_amdgcn_mfma_f32_16x16x32_bf16(kf[mt][0], qf[nq][0], v, 0, 0, 0);
                v = __builtin_amdgcn_mfma_f32_16x16x32_bf16(kf[mt][1], qf[nq][1], v, 0, 0, 0);
                st[nq][mt] = v;
            }

        // scale + mask
        #pragma unroll
        for (int nq = 0; nq < 2; ++nq)
            #pragma unroll
            for (int mt = 0; mt < 4; ++mt)
                #pragma unroll
                for (int r = 0; r < 4; ++r)
                    st[nq][mt][r] = st[nq][mt][r] * 0.125f + mkv[mt][r];

        // ---- online softmax: per-lane 16 values + 2 butterflies ----
        float alpha[2];
        #pragma unroll
        for (int nq = 0; nq < 2; ++nq) {
            float mx = st[nq][0][0];
            #pragma unroll
            for (int mt = 0; mt < 4; ++mt)
                #pragma unroll
                for (int r = 0; r < 4; ++r)
                    mx = fmaxf(mx, st[nq][mt][r]);
            mx = fmaxf(mx, __shfl_xor(mx, 16));
            mx = fmaxf(mx, __shfl_xor(mx, 32));
            float mnew = fmaxf(mst[nq], mx);
            alpha[nq] = __expf(mst[nq] - mnew);
            mst[nq] = mnew;
            float rs = 0.f;
            #pragma unroll
            for (int mt = 0; mt < 4; ++mt)
                #pragma unroll
                for (int r = 0; r < 4; ++r) {
                    float p = __expf(st[nq][mt][r] - mnew);
                    st[nq][mt][r] = p;
                    rs += p;
                }
            rs += __shfl_xor(rs, 16);
            rs += __shfl_xor(rs, 32);
            lst[nq] = lst[nq] * alpha[nq] + rs;
        }

        // ---- P -> per-wave LDS, XOR-swizzled granules (wave-private: no barrier)
        // element (qrow, key): granule g=key>>3 stored at g^(qrow&7), off=key&7
        #pragma unroll
        for (int nq = 0; nq < 2; ++nq) {
            int rowb = (nq * 16 + l15) * 64;
            #pragma unroll
            for (int mt = 0; mt < 4; ++mt) {
                int g = 2 * mt + (quad >> 1);
                int addr = rowb + ((g ^ q7) << 3) + ((quad & 1) << 2);
                uint2 d;
                d.x = pack2bf(st[nq][mt][0], st[nq][mt][1]);
                d.y = pack2bf(st[nq][mt][2], st[nq][mt][3]);
                *(uint2*)&Pw[addr] = d;
            }
        }

        // ---- P A-fragments: A[m=q][k=key], k = hh*32 + quad*8 + j ----
        bf16x8 pf[2][2];
        #pragma unroll
        for (int nq = 0; nq < 2; ++nq)
            #pragma unroll
            for (int hh = 0; hh < 2; ++hh) {
                int g = hh * 4 + quad;
                pf[nq][hh] = *(const bf16x8*)&Pw[(nq * 16 + l15) * 64 + ((g ^ q7) << 3)];
            }

        // ---- V B-fragments direct from V^T: B[k=key][n=dv] ----
        bf16x8 vf[4][2];
        #pragma unroll
        for (int dt = 0; dt < 4; ++dt)
            #pragma unroll
            for (int hh = 0; hh < 2; ++hh)
                vf[dt][hh] = *(const bf16x8*)(
                    Vp + (size_t)(dt * 16 + l15) * CS + k0 + hh * 32 + quad * 8);

        // ---- rescale O (alpha moved l15-domain -> C-layout via bpermute) ----
        float ac[2][4];
        #pragma unroll
        for (int nq = 0; nq < 2; ++nq)
            #pragma unroll
            for (int r = 0; r < 4; ++r)
                ac[nq][r] = __shfl(alpha[nq], quad * 4 + r);
        #pragma unroll
        for (int nq = 0; nq < 2; ++nq)
            #pragma unroll
            for (int dt = 0; dt < 4; ++dt)
                #pragma unroll
                for (int r = 0; r < 4; ++r)
                    O[nq][dt][r] *= ac[nq][r];

        // ---- O += P.V ----
        #pragma unroll
        for (int nq = 0; nq < 2; ++nq)
            #pragma unroll
            for (int dt = 0; dt < 4; ++dt) {
                O[nq][dt] = __builtin_amdgcn_mfma_f32_16x16x32_bf16(
                    pf[nq][0], vf[dt][0], O[nq][dt], 0, 0, 0);
                O[nq][dt] = __builtin_amdgcn_mfma_f32_16x16x32_bf16(
                    pf[nq][1], vf[dt][1], O[nq][dt], 0, 0, 0);
            }
    }

    // ---- epilogue ----
    float linv[2] = {1.f / lst[0], 1.f / lst[1]};
    float lc[2][4];
    #pragma unroll
    for (int nq = 0; nq < 2; ++nq)
        #pragma unroll
        for (int r = 0; r < 4; ++r)
            lc[nq][r] = __shfl(linv[nq], quad * 4 + r);

    #pragma unroll
    for (int nq = 0; nq < 2; ++nq)
        #pragma unroll
        for (int r = 0; r < 4; ++r) {
            int q = q0 + w * 32 + nq * 16 + quad * 4 + r;
            float* orow = out + ((size_t)b * CS + q) * CD + h * CHD;
            #pragma unroll
            for (int dt = 0; dt < 4; ++dt)
                orow[dt * 16 + l15] = O[nq][dt][r] * lc[nq][r];
        }
}

// ---------------------------------------------------------------------------
extern "C" void kernel_launch(void* const* d_in, const int* in_sizes, int n_in,
                              void* d_out, int out_size, void* d_ws, size_t ws_size,
                              hipStream_t stream)
{
    const float* X    = (const float*)d_in[0];
    const float* mask = (const float*)d_in[1];
    const float* Wq   = (const float*)d_in[2];
    const float* bq   = (const float*)d_in[3];
    const float* Wk   = (const float*)d_in[4];
    const float* bk   = (const float*)d_in[5];
    const float* Wv   = (const float*)d_in[6];
    const float* bv   = (const float*)d_in[7];
    float* out = (float*)d_out;

    char* ws = (char*)d_ws;
    u16* Xb = (u16*)(ws);                        // 8 MB
    u16* Wt = (u16*)(ws + ((size_t)8  << 20));   // 6 MB
    u16* Qb = (u16*)(ws + ((size_t)14 << 20));   // 8 MB
    u16* Kb = (u16*)(ws + ((size_t)22 << 20));   // 8 MB
    u16* Vt = (u16*)(ws + ((size_t)30 << 20));   // 8 MB

    convert_x<<<CM * CD / (256 * 8), 256, 0, stream>>>(X, Xb);
    convert_wt<<<dim3(16, 16, 3), 256, 0, stream>>>(Wq, Wk, Wv, Wt);
    qkv_gemm_mfma<<<dim3(CM / 128, CD / 128, 3), 256, 0, stream>>>(
        Xb, Wt, bq, bk, bv, Qb, Kb, Vt);
    attn_mfma<<<dim3(CS / 128, CB * CH), 256, 0, stream>>>(Qb, Kb, Vt, mask, out);
}

// Round 4
// 237.534 us; speedup vs baseline: 3.7856x; 1.0045x over previous
//
#include <hip/hip_runtime.h>
#include <math.h>

// Problem constants (B,S,D,H,HD) = (2,2048,1024,16,64)
#define CB 2
#define CS 2048
#define CD 1024
#define CH 16
#define CHD 64
#define CM (CB*CS)   // 4096 rows

#define QSCALE 0.18033688f   // 0.125 * log2(e)
#define LOG2E  1.44269504f

typedef unsigned short u16;
using bf16x8 = __attribute__((ext_vector_type(8))) short;
using u16x8  = __attribute__((ext_vector_type(8))) unsigned short;
using f32x4  = __attribute__((ext_vector_type(4))) float;

__device__ __forceinline__ u16 f2bf(float f) {
    unsigned int u = __float_as_uint(f);
    u = (u + 0x7FFFu + ((u >> 16) & 1u)) >> 16;
    return (u16)u;
}

__device__ __forceinline__ unsigned pack2bf(float a, float b) {
    unsigned ua = (__float_as_uint(a) + 0x8000u) >> 16;
    unsigned ub = (__float_as_uint(b) + 0x8000u) & 0xFFFF0000u;
    return ua | ub;
}

__device__ __forceinline__ void load_lds16(const u16* g, u16* l) {
    __builtin_amdgcn_global_load_lds(
        (const __attribute__((address_space(1))) unsigned int*)g,
        (__attribute__((address_space(3))) unsigned int*)l, 16, 0, 0);
}

// ---------------------------------------------------------------------------
__global__ __launch_bounds__(256)
void convert_x(const float* __restrict__ X, u16* __restrict__ Xb)
{
    size_t i = ((size_t)blockIdx.x * 256 + threadIdx.x) * 8;
    float4 v0 = *(const float4*)(X + i);
    float4 v1 = *(const float4*)(X + i + 4);
    u16x8 o;
    o[0] = f2bf(v0.x); o[1] = f2bf(v0.y); o[2] = f2bf(v0.z); o[3] = f2bf(v0.w);
    o[4] = f2bf(v1.x); o[5] = f2bf(v1.y); o[6] = f2bf(v1.z); o[7] = f2bf(v1.w);
    *(u16x8*)(Xb + i) = o;
}

// ---------------------------------------------------------------------------
// W [K][N] fp32 -> Wt [N][K] bf16 transposed.  z==0 (Wq) pre-scaled by QSCALE
// so attention scores come out in log2 domain.
// ---------------------------------------------------------------------------
__global__ __launch_bounds__(256)
void convert_wt(const float* __restrict__ Wq, const float* __restrict__ Wk,
                const float* __restrict__ Wv, u16* __restrict__ Wt)
{
    const int z = blockIdx.z;
    const float* W = (z == 0) ? Wq : (z == 1) ? Wk : Wv;
    const float sc = (z == 0) ? QSCALE : 1.0f;
    u16* Wo = Wt + (size_t)z * CD * CD;

    __shared__ u16 T[64][72];
    const int k0 = blockIdx.x << 6;
    const int n0 = blockIdx.y << 6;
    const int tid = threadIdx.x;

    #pragma unroll
    for (int it = 0; it < 4; ++it) {
        int r = (tid >> 4) + (it << 4);
        int c = (tid & 15) << 2;
        float4 v = *(const float4*)(W + (size_t)(k0 + r) * CD + n0 + c);
        T[c + 0][r] = f2bf(v.x * sc);
        T[c + 1][r] = f2bf(v.y * sc);
        T[c + 2][r] = f2bf(v.z * sc);
        T[c + 3][r] = f2bf(v.w * sc);
    }
    __syncthreads();
    #pragma unroll
    for (int it = 0; it < 2; ++it) {
        int cc = tid + (it << 8);
        int n  = cc >> 3;
        int ch = (cc & 7) << 3;
        *(uint4*)(Wo + (size_t)(n0 + n) * CD + k0 + ch) = *(const uint4*)&T[n][ch];
    }
}

// ---------------------------------------------------------------------------
// QKV GEMM, bf16 MFMA 16x16x32.  128x128 tile, BK=32, global_load_lds with
// XOR-swizzled chunk assignment: lane loads global chunk (l&3)^((l>>3)&3) so
// fragment ds_read_b128 at slot quad^((l15>>1)&3) is 2-way (free) instead of
// 8-way conflicted.  Q/K epilogue via LDS roundtrip -> dwordx4 stores.
// ---------------------------------------------------------------------------
__global__ __launch_bounds__(256, 3)
void qkv_gemm_mfma(const u16* __restrict__ Xb, const u16* __restrict__ Wt,
                   const float* __restrict__ bq, const float* __restrict__ bk,
                   const float* __restrict__ bv,
                   u16* __restrict__ Qb, u16* __restrict__ Kb,
                   u16* __restrict__ Vt)
{
    const int z = blockIdx.z;
    const u16* W = Wt + (size_t)z * CD * CD;
    const float* bias = (z == 0) ? bq : (z == 1) ? bk : bv;
    const float bscale = (z == 0) ? QSCALE : 1.0f;

    __shared__ u16 smem[8704];          // As 4096 + Bs 4096; epilogue reuse
    u16* As = smem;                     // [128][32] lane-linear, swizzled chunks
    u16* Bs = smem + 4096;

    const int tid  = threadIdx.x;
    const int w    = tid >> 6;
    const int l    = tid & 63;
    const int l15  = l & 15;
    const int quad = l >> 4;
    const int wm   = w >> 1;
    const int wn   = w & 1;

    const int row0 = blockIdx.x << 7;
    const int n0   = blockIdx.y << 7;

    f32x4 acc[4][4];
    #pragma unroll
    for (int mi = 0; mi < 4; ++mi)
        #pragma unroll
        for (int nt = 0; nt < 4; ++nt)
            acc[mi][nt] = (f32x4){0.f, 0.f, 0.f, 0.f};

    const u16* Ag = Xb + (size_t)row0 * CD;
    const u16* Bg = W  + (size_t)n0   * CD;
    const int lr = l >> 2;                          // row within 16-row chunk
    const int lg = ((l & 3) ^ ((l >> 3) & 3)) << 3; // swizzled global chunk (u16)
    const int fs = (quad ^ ((l15 >> 1) & 3)) << 3;  // fragment slot (u16)

    for (int k0 = 0; k0 < CD; k0 += 32) {
        __syncthreads();
        #pragma unroll
        for (int i = 0; i < 2; ++i) {
            int c = w * 2 + i;
            load_lds16(Ag + (size_t)(c * 16 + lr) * CD + k0 + lg, As + c * 512);
            load_lds16(Bg + (size_t)(c * 16 + lr) * CD + k0 + lg, Bs + c * 512);
        }
        __syncthreads();

        bf16x8 af[4], bfr[4];
        #pragma unroll
        for (int mi = 0; mi < 4; ++mi)
            af[mi] = *(const bf16x8*)&As[(wm * 64 + mi * 16 + l15) * 32 + fs];
        #pragma unroll
        for (int nt = 0; nt < 4; ++nt)
            bfr[nt] = *(const bf16x8*)&Bs[(wn * 64 + nt * 16 + l15) * 32 + fs];
        #pragma unroll
        for (int mi = 0; mi < 4; ++mi)
            #pragma unroll
            for (int nt = 0; nt < 4; ++nt)
                acc[mi][nt] = __builtin_amdgcn_mfma_f32_16x16x32_bf16(
                    af[mi], bfr[nt], acc[mi][nt], 0, 0, 0);
    }

    __syncthreads();   // K-loop LDS reads done; smem reusable

    if (z < 2) {
        u16* Og = (z == 0) ? Qb : Kb;
        float bb[4];
        #pragma unroll
        for (int nt = 0; nt < 4; ++nt)
            bb[nt] = bias[n0 + wn * 64 + nt * 16 + l15] * bscale;

        u16 (*Ct)[136] = (u16(*)[136])smem;   // [row 0..63][col 0..127]
        #pragma unroll
        for (int mh = 0; mh < 2; ++mh) {
            if (wm == mh) {
                #pragma unroll
                for (int nt = 0; nt < 4; ++nt)
                    #pragma unroll
                    for (int mi = 0; mi < 4; ++mi)
                        #pragma unroll
                        for (int r = 0; r < 4; ++r)
                            Ct[mi * 16 + quad * 4 + r][wn * 64 + nt * 16 + l15] =
                                f2bf(acc[mi][nt][r] + bb[nt]);
            }
            __syncthreads();
            #pragma unroll
            for (int it = 0; it < 4; ++it) {
                int c  = tid + (it << 8);
                int rl = c >> 4;
                int ck = c & 15;
                uint4 d = *(const uint4*)&Ct[rl][ck * 8];
                int gcol = n0 + ck * 8;
                int h = gcol >> 6, hd = gcol & 63;
                int m = row0 + mh * 64 + rl;
                int b = m >> 11, s = m & (CS - 1);
                *(uint4*)(Og + ((size_t)(b * CH + h) * CS + s) * CHD + hd) = d;
            }
            __syncthreads();
        }
    } else {
        // V: transpose -> [b,h,hd,s]
        u16 (*Ct)[136] = (u16(*)[136])smem;
        #pragma unroll
        for (int nh = 0; nh < 2; ++nh) {
            if (wn == nh) {
                #pragma unroll
                for (int nt = 0; nt < 4; ++nt) {
                    int col = n0 + nh * 64 + nt * 16 + l15;
                    float bb = bias[col];
                    #pragma unroll
                    for (int mi = 0; mi < 4; ++mi)
                        #pragma unroll
                        for (int r = 0; r < 4; ++r) {
                            int ml = wm * 64 + mi * 16 + quad * 4 + r;
                            Ct[nt * 16 + l15][ml] = f2bf(acc[mi][nt][r] + bb);
                        }
                }
            }
            __syncthreads();
            #pragma unroll
            for (int it = 0; it < 4; ++it) {
                int c   = tid + (it << 8);
                int dvl = c >> 4;
                int ch  = c & 15;
                uint4 vdat = *(const uint4*)&Ct[dvl][ch * 8];
                int col = n0 + nh * 64 + dvl;
                int h   = col >> 6;
                int dv  = col & 63;
                int m0  = row0 + ch * 8;
                int b   = m0 >> 11;
                int s0  = m0 & (CS - 1);
                *(uint4*)(Vt + (((size_t)(b * CH + h)) * CHD + dv) * CS + s0) = vdat;
            }
            __syncthreads();
        }
    }
}

// ---------------------------------------------------------------------------
// Flash attention v3: S^T = K.Q^T, barrier-free K-loop, explicit 2-stage
// register pipeline on K fragments (kfA/kfB), V+mask issued at tile top.
// Softmax in exp2 domain (Q pre-scaled by QSCALE; mask staged * LOG2E).
// alpha/linv broadcast col->row domain via wave-private LDS b128 reads.
// ---------------------------------------------------------------------------
__global__ __launch_bounds__(256, 2)
void attn_mfma(const u16* __restrict__ Qg, const u16* __restrict__ Kg,
               const u16* __restrict__ Vtg, const float* __restrict__ mask,
               float* __restrict__ out)
{
    __shared__ float msk[CS];           // mask * LOG2E
    __shared__ u16   Pl[4][32 * 64];    // per-wave P buffers
    __shared__ float abuf[4][32];       // per-wave alpha broadcast

    const int q0  = blockIdx.x << 7;
    const int bh  = blockIdx.y;
    const int b   = bh >> 4;
    const int h   = bh & 15;
    const int tid = threadIdx.x;
    const int w    = tid >> 6;
    const int l    = tid & 63;
    const int l15  = l & 15;
    const int quad = l >> 4;
    const int q7   = l15 & 7;

    const u16* Qp = Qg  + (size_t)bh * CS * CHD;
    const u16* Kp = Kg  + (size_t)bh * CS * CHD;
    const u16* Vp = Vtg + (size_t)bh * CHD * CS;
    const float* mrow = mask + (size_t)b * CS;

    {
        int i = tid * 8;
        float4 a = *(const float4*)(mrow + i);
        float4 c = *(const float4*)(mrow + i + 4);
        msk[i + 0] = a.x * LOG2E; msk[i + 1] = a.y * LOG2E;
        msk[i + 2] = a.z * LOG2E; msk[i + 3] = a.w * LOG2E;
        msk[i + 4] = c.x * LOG2E; msk[i + 5] = c.y * LOG2E;
        msk[i + 6] = c.z * LOG2E; msk[i + 7] = c.w * LOG2E;
    }
    __syncthreads();

    u16* Pw = &Pl[w][0];

    bf16x8 qf[2][2];
    #pragma unroll
    for (int nq = 0; nq < 2; ++nq)
        #pragma unroll
        for (int hh = 0; hh < 2; ++hh)
            qf[nq][hh] = *(const bf16x8*)(
                Qp + (size_t)(q0 + w * 32 + nq * 16 + l15) * CHD + hh * 32 + quad * 8);

    float mst[2] = {-3.0e38f, -3.0e38f};
    float lst[2] = {0.f, 0.f};
    f32x4 O[2][4];
    #pragma unroll
    for (int nq = 0; nq < 2; ++nq)
        #pragma unroll
        for (int dt = 0; dt < 4; ++dt)
            O[nq][dt] = (f32x4){0.f, 0.f, 0.f, 0.f};

    bf16x8 kfA[4][2], kfB[4][2];
    // prologue: tile 0 K fragments
    #pragma unroll
    for (int mt = 0; mt < 4; ++mt)
        #pragma unroll
        for (int hh = 0; hh < 2; ++hh)
            kfA[mt][hh] = *(const bf16x8*)(
                Kp + (size_t)(mt * 16 + l15) * CHD + hh * 32 + quad * 8);

    auto step = [&](int kc, int kn, bf16x8 (&kfu)[4][2], bf16x8 (&kfl)[4][2]) {
        // --- issue next-tile K loads + this-tile V loads first (ILP) ---
        #pragma unroll
        for (int mt = 0; mt < 4; ++mt)
            #pragma unroll
            for (int hh = 0; hh < 2; ++hh)
                kfl[mt][hh] = *(const bf16x8*)(
                    Kp + (size_t)(kn + mt * 16 + l15) * CHD + hh * 32 + quad * 8);
        bf16x8 vf[4][2];
        #pragma unroll
        for (int dt = 0; dt < 4; ++dt)
            #pragma unroll
            for (int hh = 0; hh < 2; ++hh)
                vf[dt][hh] = *(const bf16x8*)(
                    Vp + (size_t)(dt * 16 + l15) * CS + kc + hh * 32 + quad * 8);
        f32x4 mkv[4];
        #pragma unroll
        for (int mt = 0; mt < 4; ++mt)
            mkv[mt] = *(const f32x4*)&msk[kc + mt * 16 + quad * 4];

        // --- S^T = K.Q^T (log2 domain; Q pre-scaled) ---
        f32x4 st[2][4];
        #pragma unroll
        for (int nq = 0; nq < 2; ++nq)
            #pragma unroll
            for (int mt = 0; mt < 4; ++mt) {
                f32x4 v = (f32x4){0.f, 0.f, 0.f, 0.f};
                v = __builtin_amdgcn_mfma_f32_16x16x32_bf16(kfu[mt][0], qf[nq][0], v, 0, 0, 0);
                v = __builtin_amdgcn_mfma_f32_16x16x32_bf16(kfu[mt][1], qf[nq][1], v, 0, 0, 0);
                st[nq][mt] = v;
            }
        #pragma unroll
        for (int nq = 0; nq < 2; ++nq)
            #pragma unroll
            for (int mt = 0; mt < 4; ++mt)
                #pragma unroll
                for (int r = 0; r < 4; ++r)
                    st[nq][mt][r] += mkv[mt][r];

        // --- online softmax, exp2 domain ---
        float alpha[2];
        #pragma unroll
        for (int nq = 0; nq < 2; ++nq) {
            float mx = st[nq][0][0];
            #pragma unroll
            for (int mt = 0; mt < 4; ++mt)
                #pragma unroll
                for (int r = 0; r < 4; ++r)
                    mx = fmaxf(mx, st[nq][mt][r]);
            mx = fmaxf(mx, __shfl_xor(mx, 16));
            mx = fmaxf(mx, __shfl_xor(mx, 32));
            float mnew = fmaxf(mst[nq], mx);
            alpha[nq] = exp2f(mst[nq] - mnew);
            mst[nq] = mnew;
            float rs = 0.f;
            #pragma unroll
            for (int mt = 0; mt < 4; ++mt)
                #pragma unroll
                for (int r = 0; r < 4; ++r) {
                    float p = exp2f(st[nq][mt][r] - mnew);
                    st[nq][mt][r] = p;
                    rs += p;
                }
            rs += __shfl_xor(rs, 16);
            rs += __shfl_xor(rs, 32);
            lst[nq] = lst[nq] * alpha[nq] + rs;
        }

        // --- P -> wave-private LDS (XOR-swizzled) ---
        #pragma unroll
        for (int nq = 0; nq < 2; ++nq) {
            int rowb = (nq * 16 + l15) * 64;
            #pragma unroll
            for (int mt = 0; mt < 4; ++mt) {
                int g = 2 * mt + (quad >> 1);
                int addr = rowb + ((g ^ q7) << 3) + ((quad & 1) << 2);
                uint2 d;
                d.x = pack2bf(st[nq][mt][0], st[nq][mt][1]);
                d.y = pack2bf(st[nq][mt][2], st[nq][mt][3]);
                *(uint2*)&Pw[addr] = d;
            }
        }

        // --- alpha broadcast col->row domain via wave-private LDS ---
        if (quad == 0) {
            abuf[w][l15]      = alpha[0];
            abuf[w][16 + l15] = alpha[1];
        }
        f32x4 ac0 = *(const f32x4*)&abuf[w][quad * 4];
        f32x4 ac1 = *(const f32x4*)&abuf[w][16 + quad * 4];

        bf16x8 pf[2][2];
        #pragma unroll
        for (int nq = 0; nq < 2; ++nq)
            #pragma unroll
            for (int hh = 0; hh < 2; ++hh) {
                int g = hh * 4 + quad;
                pf[nq][hh] = *(const bf16x8*)&Pw[(nq * 16 + l15) * 64 + ((g ^ q7) << 3)];
            }

        #pragma unroll
        for (int dt = 0; dt < 4; ++dt)
            #pragma unroll
            for (int r = 0; r < 4; ++r) {
                O[0][dt][r] *= ac0[r];
                O[1][dt][r] *= ac1[r];
            }

        // --- O += P.V ---
        #pragma unroll
        for (int nq = 0; nq < 2; ++nq)
            #pragma unroll
            for (int dt = 0; dt < 4; ++dt) {
                O[nq][dt] = __builtin_amdgcn_mfma_f32_16x16x32_bf16(
                    pf[nq][0], vf[dt][0], O[nq][dt], 0, 0, 0);
                O[nq][dt] = __builtin_amdgcn_mfma_f32_16x16x32_bf16(
                    pf[nq][1], vf[dt][1], O[nq][dt], 0, 0, 0);
            }
    };

    for (int k0 = 0; k0 < CS; k0 += 128) {
        step(k0,      k0 + 64,              kfA, kfB);
        step(k0 + 64, (k0 + 128) & (CS - 1), kfB, kfA);
    }

    // ---- epilogue ----
    float linv[2] = {1.f / lst[0], 1.f / lst[1]};
    float lc[2][4];
    #pragma unroll
    for (int nq = 0; nq < 2; ++nq)
        #pragma unroll
        for (int r = 0; r < 4; ++r)
            lc[nq][r] = __shfl(linv[nq], quad * 4 + r);

    #pragma unroll
    for (int nq = 0; nq < 2; ++nq)
        #pragma unroll
        for (int r = 0; r < 4; ++r) {
            int q = q0 + w * 32 + nq * 16 + quad * 4 + r;
            float* orow = out + ((size_t)b * CS + q) * CD + h * CHD;
            #pragma unroll
            for (int dt = 0; dt < 4; ++dt)
                orow[dt * 16 + l15] = O[nq][dt][r] * lc[nq][r];
        }
}

// ---------------------------------------------------------------------------
extern "C" void kernel_launch(void* const* d_in, const int* in_sizes, int n_in,
                              void* d_out, int out_size, void* d_ws, size_t ws_size,
                              hipStream_t stream)
{
    const float* X    = (const float*)d_in[0];
    const float* mask = (const float*)d_in[1];
    const float* Wq   = (const float*)d_in[2];
    const float* bq   = (const float*)d_in[3];
    const float* Wk   = (const float*)d_in[4];
    const float* bk   = (const float*)d_in[5];
    const float* Wv   = (const float*)d_in[6];
    const float* bv   = (const float*)d_in[7];
    float* out = (float*)d_out;

    char* ws = (char*)d_ws;
    u16* Xb = (u16*)(ws);
    u16* Wt = (u16*)(ws + ((size_t)8  << 20));
    u16* Qb = (u16*)(ws + ((size_t)14 << 20));
    u16* Kb = (u16*)(ws + ((size_t)22 << 20));
    u16* Vt = (u16*)(ws + ((size_t)30 << 20));

    convert_x<<<CM * CD / (256 * 8), 256, 0, stream>>>(X, Xb);
    convert_wt<<<dim3(16, 16, 3), 256, 0, stream>>>(Wq, Wk, Wv, Wt);
    qkv_gemm_mfma<<<dim3(CM / 128, CD / 128, 3), 256, 0, stream>>>(
        Xb, Wt, bq, bk, bv, Qb, Kb, Vt);
    attn_mfma<<<dim3(CS / 128, CB * CH), 256, 0, stream>>>(Qb, Kb, Vt, mask, out);
}

// Round 5
// 232.958 us; speedup vs baseline: 3.8599x; 1.0196x over previous
//
#include <hip/hip_runtime.h>
#include <math.h>

// Problem constants (B,S,D,H,HD) = (2,2048,1024,16,64)
#define CB 2
#define CS 2048
#define CD 1024
#define CH 16
#define CHD 64
#define CM (CB*CS)   // 4096 rows

#define QSCALE 0.18033688f   // 0.125 * log2(e)
#define LOG2E  1.44269504f
#define BLOG   40.0f         // static softmax bound (log2 domain)

typedef unsigned short u16;
using bf16x8 = __attribute__((ext_vector_type(8))) short;
using u16x8  = __attribute__((ext_vector_type(8))) unsigned short;
using f32x4  = __attribute__((ext_vector_type(4))) float;

__device__ __forceinline__ u16 f2bf(float f) {
    unsigned int u = __float_as_uint(f);
    u = (u + 0x7FFFu + ((u >> 16) & 1u)) >> 16;
    return (u16)u;
}

__device__ __forceinline__ unsigned pack2bf(float a, float b) {
    unsigned ua = (__float_as_uint(a) + 0x8000u) >> 16;
    unsigned ub = (__float_as_uint(b) + 0x8000u) & 0xFFFF0000u;
    return ua | ub;
}

__device__ __forceinline__ void load_lds16(const u16* g, u16* l) {
    __builtin_amdgcn_global_load_lds(
        (const __attribute__((address_space(1))) unsigned int*)g,
        (__attribute__((address_space(3))) unsigned int*)l, 16, 0, 0);
}

// ---------------------------------------------------------------------------
__global__ __launch_bounds__(256)
void convert_x(const float* __restrict__ X, u16* __restrict__ Xb)
{
    size_t i = ((size_t)blockIdx.x * 256 + threadIdx.x) * 8;
    float4 v0 = *(const float4*)(X + i);
    float4 v1 = *(const float4*)(X + i + 4);
    u16x8 o;
    o[0] = f2bf(v0.x); o[1] = f2bf(v0.y); o[2] = f2bf(v0.z); o[3] = f2bf(v0.w);
    o[4] = f2bf(v1.x); o[5] = f2bf(v1.y); o[6] = f2bf(v1.z); o[7] = f2bf(v1.w);
    *(u16x8*)(Xb + i) = o;
}

// ---------------------------------------------------------------------------
// W [K][N] fp32 -> Wt [N][K] bf16 transposed; Wq pre-scaled by QSCALE.
// ---------------------------------------------------------------------------
__global__ __launch_bounds__(256)
void convert_wt(const float* __restrict__ Wq, const float* __restrict__ Wk,
                const float* __restrict__ Wv, u16* __restrict__ Wt)
{
    const int z = blockIdx.z;
    const float* W = (z == 0) ? Wq : (z == 1) ? Wk : Wv;
    const float sc = (z == 0) ? QSCALE : 1.0f;
    u16* Wo = Wt + (size_t)z * CD * CD;

    __shared__ u16 T[64][72];
    const int k0 = blockIdx.x << 6;
    const int n0 = blockIdx.y << 6;
    const int tid = threadIdx.x;

    #pragma unroll
    for (int it = 0; it < 4; ++it) {
        int r = (tid >> 4) + (it << 4);
        int c = (tid & 15) << 2;
        float4 v = *(const float4*)(W + (size_t)(k0 + r) * CD + n0 + c);
        T[c + 0][r] = f2bf(v.x * sc);
        T[c + 1][r] = f2bf(v.y * sc);
        T[c + 2][r] = f2bf(v.z * sc);
        T[c + 3][r] = f2bf(v.w * sc);
    }
    __syncthreads();
    #pragma unroll
    for (int it = 0; it < 2; ++it) {
        int cc = tid + (it << 8);
        int n  = cc >> 3;
        int ch = (cc & 7) << 3;
        *(uint4*)(Wo + (size_t)(n0 + n) * CD + k0 + ch) = *(const uint4*)&T[n][ch];
    }
}

// ---------------------------------------------------------------------------
// QKV GEMM, bf16 MFMA 16x16x32.  128x128 tile, BK=64 (half the barriers of
// BK=32), global_load_lds staging with 8-slot XOR swizzle:
//   stored slot s = g ^ (row & 7)  (g = 16B chunk index 0..7 in the 64-u16 row)
// so fragment ds_read_b128 at slot (kk*4+quad)^(l15&7) hits all 32 banks
// uniformly (8 dwords/bank = minimum).
// ---------------------------------------------------------------------------
__global__ __launch_bounds__(256, 3)
void qkv_gemm_mfma(const u16* __restrict__ Xb, const u16* __restrict__ Wt,
                   const float* __restrict__ bq, const float* __restrict__ bk,
                   const float* __restrict__ bv,
                   u16* __restrict__ Qb, u16* __restrict__ Kb,
                   u16* __restrict__ Vt)
{
    const int z = blockIdx.z;
    const u16* W = Wt + (size_t)z * CD * CD;
    const float* bias = (z == 0) ? bq : (z == 1) ? bk : bv;
    const float bscale = (z == 0) ? QSCALE : 1.0f;

    __shared__ u16 smem[16384];         // As [128][64] + Bs [128][64] = 32 KB
    u16* As = smem;
    u16* Bs = smem + 8192;

    const int tid  = threadIdx.x;
    const int w    = tid >> 6;
    const int l    = tid & 63;
    const int l15  = l & 15;
    const int quad = l >> 4;
    const int wm   = w >> 1;
    const int wn   = w & 1;

    const int row0 = blockIdx.x << 7;
    const int n0   = blockIdx.y << 7;

    f32x4 acc[4][4];
    #pragma unroll
    for (int mi = 0; mi < 4; ++mi)
        #pragma unroll
        for (int nt = 0; nt < 4; ++nt)
            acc[mi][nt] = (f32x4){0.f, 0.f, 0.f, 0.f};

    const u16* Ag = Xb + (size_t)row0 * CD;
    const u16* Bg = W  + (size_t)n0   * CD;
    const int lr8 = l >> 3;                 // 0..7: row within 8-row group
    const int ls  = l & 7;                  // stored slot
    const int lg  = (ls ^ lr8) << 3;        // global chunk offset (u16)
    const int q7  = l15 & 7;

    for (int k0 = 0; k0 < CD; k0 += 64) {
        __syncthreads();
        #pragma unroll
        for (int i = 0; i < 4; ++i) {
            int r = w * 32 + 8 * i + lr8;
            load_lds16(Ag + (size_t)r * CD + k0 + lg, As + (size_t)(w * 32 + 8 * i) * 64);
            load_lds16(Bg + (size_t)r * CD + k0 + lg, Bs + (size_t)(w * 32 + 8 * i) * 64);
        }
        __syncthreads();

        #pragma unroll
        for (int kk = 0; kk < 2; ++kk) {
            bf16x8 af[4], bfr[4];
            #pragma unroll
            for (int mi = 0; mi < 4; ++mi)
                af[mi] = *(const bf16x8*)
                    &As[(wm * 64 + mi * 16 + l15) * 64 + (((kk * 4 + quad) ^ q7) << 3)];
            #pragma unroll
            for (int nt = 0; nt < 4; ++nt)
                bfr[nt] = *(const bf16x8*)
                    &Bs[(wn * 64 + nt * 16 + l15) * 64 + (((kk * 4 + quad) ^ q7) << 3)];
            #pragma unroll
            for (int mi = 0; mi < 4; ++mi)
                #pragma unroll
                for (int nt = 0; nt < 4; ++nt)
                    acc[mi][nt] = __builtin_amdgcn_mfma_f32_16x16x32_bf16(
                        af[mi], bfr[nt], acc[mi][nt], 0, 0, 0);
        }
    }

    __syncthreads();   // K-loop LDS reads done; smem reusable

    if (z < 2) {
        u16* Og = (z == 0) ? Qb : Kb;
        float bb[4];
        #pragma unroll
        for (int nt = 0; nt < 4; ++nt)
            bb[nt] = bias[n0 + wn * 64 + nt * 16 + l15] * bscale;

        u16 (*Ct)[136] = (u16(*)[136])smem;
        #pragma unroll
        for (int mh = 0; mh < 2; ++mh) {
            if (wm == mh) {
                #pragma unroll
                for (int nt = 0; nt < 4; ++nt)
                    #pragma unroll
                    for (int mi = 0; mi < 4; ++mi)
                        #pragma unroll
                        for (int r = 0; r < 4; ++r)
                            Ct[mi * 16 + quad * 4 + r][wn * 64 + nt * 16 + l15] =
                                f2bf(acc[mi][nt][r] + bb[nt]);
            }
            __syncthreads();
            #pragma unroll
            for (int it = 0; it < 4; ++it) {
                int c  = tid + (it << 8);
                int rl = c >> 4;
                int ck = c & 15;
                uint4 d = *(const uint4*)&Ct[rl][ck * 8];
                int gcol = n0 + ck * 8;
                int h = gcol >> 6, hd = gcol & 63;
                int m = row0 + mh * 64 + rl;
                int b = m >> 11, s = m & (CS - 1);
                *(uint4*)(Og + ((size_t)(b * CH + h) * CS + s) * CHD + hd) = d;
            }
            __syncthreads();
        }
    } else {
        u16 (*Ct)[136] = (u16(*)[136])smem;
        #pragma unroll
        for (int nh = 0; nh < 2; ++nh) {
            if (wn == nh) {
                #pragma unroll
                for (int nt = 0; nt < 4; ++nt) {
                    int col = n0 + nh * 64 + nt * 16 + l15;
                    float bb = bias[col];
                    #pragma unroll
                    for (int mi = 0; mi < 4; ++mi)
                        #pragma unroll
                        for (int r = 0; r < 4; ++r) {
                            int ml = wm * 64 + mi * 16 + quad * 4 + r;
                            Ct[nt * 16 + l15][ml] = f2bf(acc[mi][nt][r] + bb);
                        }
                }
            }
            __syncthreads();
            #pragma unroll
            for (int it = 0; it < 4; ++it) {
                int c   = tid + (it << 8);
                int dvl = c >> 4;
                int ch  = c & 15;
                uint4 vdat = *(const uint4*)&Ct[dvl][ch * 8];
                int col = n0 + nh * 64 + dvl;
                int h   = col >> 6;
                int dv  = col & 63;
                int m0  = row0 + ch * 8;
                int b   = m0 >> 11;
                int s0  = m0 & (CS - 1);
                *(uint4*)(Vt + (((size_t)(b * CH + h)) * CHD + dv) * CS + s0) = vdat;
            }
            __syncthreads();
        }
    }
}

// ---------------------------------------------------------------------------
// Flash attention v5: static-bound softmax (no running max), in-block k-split.
// Grid (S/64, B*H), block 256 = 4 waves.  Wave w: q-half qh=w&1 (32 q rows),
// k-half kh=w>>1 (1024 keys, 16 tiles of 64).  S^T = K.Q^T so each q lives at
// lane col l15; p = exp2(S + mask*log2e - B); l is a pure per-lane accumulator
// (2 shfls total).  P round-trips a wave-private XOR-swizzled LDS buffer.
// k-halves combine linearly at the end through LDS (P buffers reused).
// ---------------------------------------------------------------------------
__global__ __launch_bounds__(256, 4)
void attn_mfma(const u16* __restrict__ Qg, const u16* __restrict__ Kg,
               const u16* __restrict__ Vtg, const float* __restrict__ mask,
               float* __restrict__ out)
{
    __shared__ float msk[CS];           // 8 KB: mask*log2e - B
    __shared__ u16   Pl[4][32 * 64];    // 16 KB: per-wave P; reused as O-combine
    __shared__ float abuf[4][32];       // per-wave l broadcast

    const int q0  = blockIdx.x << 6;
    const int bh  = blockIdx.y;
    const int b   = bh >> 4;
    const int h   = bh & 15;
    const int tid = threadIdx.x;
    const int w    = tid >> 6;
    const int l    = tid & 63;
    const int l15  = l & 15;
    const int quad = l >> 4;
    const int qh   = w & 1;             // q-half
    const int kh   = w >> 1;            // k-half
    const int q7   = l15 & 7;

    const u16* Qp = Qg  + (size_t)bh * CS * CHD;
    const u16* Kp = Kg  + (size_t)bh * CS * CHD + (size_t)(kh * 1024) * CHD;
    const u16* Vp = Vtg + (size_t)bh * CHD * CS + kh * 1024;
    const float* mrow = mask + (size_t)b * CS;

    {
        int i = tid * 8;
        float4 a = *(const float4*)(mrow + i);
        float4 c = *(const float4*)(mrow + i + 4);
        msk[i + 0] = a.x * LOG2E - BLOG; msk[i + 1] = a.y * LOG2E - BLOG;
        msk[i + 2] = a.z * LOG2E - BLOG; msk[i + 3] = a.w * LOG2E - BLOG;
        msk[i + 4] = c.x * LOG2E - BLOG; msk[i + 5] = c.y * LOG2E - BLOG;
        msk[i + 6] = c.z * LOG2E - BLOG; msk[i + 7] = c.w * LOG2E - BLOG;
    }
    __syncthreads();

    u16* Pw = &Pl[w][0];
    const float* mskh = msk + kh * 1024;

    // Q B-fragments (regs, whole loop): q = q0 + qh*32 + nq*16 + l15
    bf16x8 qf[2][2];
    #pragma unroll
    for (int nq = 0; nq < 2; ++nq)
        #pragma unroll
        for (int hh = 0; hh < 2; ++hh)
            qf[nq][hh] = *(const bf16x8*)(
                Qp + (size_t)(q0 + qh * 32 + nq * 16 + l15) * CHD + hh * 32 + quad * 8);

    float lsum[2] = {0.f, 0.f};
    f32x4 O[2][4];
    #pragma unroll
    for (int nq = 0; nq < 2; ++nq)
        #pragma unroll
        for (int dt = 0; dt < 4; ++dt)
            O[nq][dt] = (f32x4){0.f, 0.f, 0.f, 0.f};

    for (int kt = 0; kt < 16; ++kt) {
        const int k0 = kt << 6;

        // K A-fragments direct from global
        bf16x8 kf[4][2];
        #pragma unroll
        for (int mt = 0; mt < 4; ++mt)
            #pragma unroll
            for (int hh = 0; hh < 2; ++hh)
                kf[mt][hh] = *(const bf16x8*)(
                    Kp + (size_t)(k0 + mt * 16 + l15) * CHD + hh * 32 + quad * 8);

        // S^T + exp2 + pack, nq-sequenced to bound register pressure
        #pragma unroll
        for (int nq = 0; nq < 2; ++nq) {
            f32x4 st[4];
            #pragma unroll
            for (int mt = 0; mt < 4; ++mt) {
                f32x4 c0 = *(const f32x4*)&mskh[k0 + mt * 16 + quad * 4];  // C-init = mask
                c0 = __builtin_amdgcn_mfma_f32_16x16x32_bf16(kf[mt][0], qf[nq][0], c0, 0, 0, 0);
                st[mt] = __builtin_amdgcn_mfma_f32_16x16x32_bf16(kf[mt][1], qf[nq][1], c0, 0, 0, 0);
            }
            float rs = lsum[nq];
            #pragma unroll
            for (int mt = 0; mt < 4; ++mt) {
                #pragma unroll
                for (int r = 0; r < 4; ++r) {
                    st[mt][r] = exp2f(st[mt][r]);
                    rs += st[mt][r];
                }
                int g = 2 * mt + (quad >> 1);
                int addr = (nq * 16 + l15) * 64 + ((g ^ q7) << 3) + ((quad & 1) << 2);
                uint2 d;
                d.x = pack2bf(st[mt][0], st[mt][1]);
                d.y = pack2bf(st[mt][2], st[mt][3]);
                *(uint2*)&Pw[addr] = d;
            }
            lsum[nq] = rs;
        }

        // P A-fragments back from wave-private LDS
        bf16x8 pf[2][2];
        #pragma unroll
        for (int nq = 0; nq < 2; ++nq)
            #pragma unroll
            for (int hh = 0; hh < 2; ++hh)
                pf[nq][hh] = *(const bf16x8*)
                    &Pw[(nq * 16 + l15) * 64 + (((hh * 4 + quad) ^ q7) << 3)];

        // V^T B-fragments direct from global
        bf16x8 vf[4][2];
        #pragma unroll
        for (int dt = 0; dt < 4; ++dt)
            #pragma unroll
            for (int hh = 0; hh < 2; ++hh)
                vf[dt][hh] = *(const bf16x8*)(
                    Vp + (size_t)(dt * 16 + l15) * CS + k0 + hh * 32 + quad * 8);

        // O += P.V   (no rescale: static bound)
        #pragma unroll
        for (int nq = 0; nq < 2; ++nq)
            #pragma unroll
            for (int dt = 0; dt < 4; ++dt) {
                O[nq][dt] = __builtin_amdgcn_mfma_f32_16x16x32_bf16(
                    pf[nq][0], vf[dt][0], O[nq][dt], 0, 0, 0);
                O[nq][dt] = __builtin_amdgcn_mfma_f32_16x16x32_bf16(
                    pf[nq][1], vf[dt][1], O[nq][dt], 0, 0, 0);
            }
    }

    // ---- l reduce across quads (only 2 shfls per nq in the whole kernel) ----
    #pragma unroll
    for (int nq = 0; nq < 2; ++nq) {
        lsum[nq] += __shfl_xor(lsum[nq], 16);
        lsum[nq] += __shfl_xor(lsum[nq], 32);
    }
    if (quad == 0) {
        abuf[w][l15]      = lsum[0];
        abuf[w][16 + l15] = lsum[1];
    }

    __syncthreads();   // all waves done with P buffers + abuf written

    if (kh == 1) {
        // dump raw O partials into the (dead) P region: wave 2 -> floats [0,2048),
        // wave 3 -> [2048,4096)  (each 32 q x 64 dv fp32 = 8 KB)
        float* ob = (float*)(&Pl[0][0]) + qh * 2048;
        #pragma unroll
        for (int nq = 0; nq < 2; ++nq)
            #pragma unroll
            for (int dt = 0; dt < 4; ++dt)
                #pragma unroll
                for (int r = 0; r < 4; ++r)
                    ob[(nq * 16 + quad * 4 + r) * 64 + dt * 16 + l15] = O[nq][dt][r];
    }
    __syncthreads();

    if (kh == 0) {
        const float* ob = (const float*)(&Pl[0][0]) + qh * 2048;
        #pragma unroll
        for (int nq = 0; nq < 2; ++nq) {
            f32x4 lo = *(const f32x4*)&abuf[w][nq * 16 + quad * 4];
            f32x4 lp = *(const f32x4*)&abuf[w + 2][nq * 16 + quad * 4];
            #pragma unroll
            for (int r = 0; r < 4; ++r) {
                float inv = 1.0f / (lo[r] + lp[r]);
                int q = q0 + qh * 32 + nq * 16 + quad * 4 + r;
                float* orow = out + ((size_t)b * CS + q) * CD + h * CHD;
                #pragma unroll
                for (int dt = 0; dt < 4; ++dt)
                    orow[dt * 16 + l15] =
                        (O[nq][dt][r] + ob[(nq * 16 + quad * 4 + r) * 64 + dt * 16 + l15]) * inv;
            }
        }
    }
}

// ---------------------------------------------------------------------------
extern "C" void kernel_launch(void* const* d_in, const int* in_sizes, int n_in,
                              void* d_out, int out_size, void* d_ws, size_t ws_size,
                              hipStream_t stream)
{
    const float* X    = (const float*)d_in[0];
    const float* mask = (const float*)d_in[1];
    const float* Wq   = (const float*)d_in[2];
    const float* bq   = (const float*)d_in[3];
    const float* Wk   = (const float*)d_in[4];
    const float* bk   = (const float*)d_in[5];
    const float* Wv   = (const float*)d_in[6];
    const float* bv   = (const float*)d_in[7];
    float* out = (float*)d_out;

    char* ws = (char*)d_ws;
    u16* Xb = (u16*)(ws);
    u16* Wt = (u16*)(ws + ((size_t)8  << 20));
    u16* Qb = (u16*)(ws + ((size_t)14 << 20));
    u16* Kb = (u16*)(ws + ((size_t)22 << 20));
    u16* Vt = (u16*)(ws + ((size_t)30 << 20));

    convert_x<<<CM * CD / (256 * 8), 256, 0, stream>>>(X, Xb);
    convert_wt<<<dim3(16, 16, 3), 256, 0, stream>>>(Wq, Wk, Wv, Wt);
    qkv_gemm_mfma<<<dim3(CM / 128, CD / 128, 3), 256, 0, stream>>>(
        Xb, Wt, bq, bk, bv, Qb, Kb, Vt);
    attn_mfma<<<dim3(CS / 64, CB * CH), 256, 0, stream>>>(Qb, Kb, Vt, mask, out);
}

// Round 6
// 194.734 us; speedup vs baseline: 4.6176x; 1.1963x over previous
//
#include <hip/hip_runtime.h>
#include <math.h>

// Problem constants (B,S,D,H,HD) = (2,2048,1024,16,64)
#define CB 2
#define CS 2048
#define CD 1024
#define CH 16
#define CHD 64
#define CM (CB*CS)   // 4096 rows

#define QSCALE 0.18033688f   // 0.125 * log2(e)
#define LOG2E  1.44269504f
#define BLOG   40.0f         // static softmax bound (log2 domain)

typedef unsigned short u16;
using bf16x8 = __attribute__((ext_vector_type(8))) short;
using u16x8  = __attribute__((ext_vector_type(8))) unsigned short;
using f32x4  = __attribute__((ext_vector_type(4))) float;

__device__ __forceinline__ u16 f2bf(float f) {
    unsigned int u = __float_as_uint(f);
    u = (u + 0x7FFFu + ((u >> 16) & 1u)) >> 16;
    return (u16)u;
}

__device__ __forceinline__ unsigned pack2bf(float a, float b) {
    unsigned ua = (__float_as_uint(a) + 0x8000u) >> 16;
    unsigned ub = (__float_as_uint(b) + 0x8000u) & 0xFFFF0000u;
    return ua | ub;
}

__device__ __forceinline__ void load_lds16(const u16* g, u16* l) {
    __builtin_amdgcn_global_load_lds(
        (const __attribute__((address_space(1))) unsigned int*)g,
        (__attribute__((address_space(3))) unsigned int*)l, 16, 0, 0);
}

// ---------------------------------------------------------------------------
__global__ __launch_bounds__(256)
void convert_x(const float* __restrict__ X, u16* __restrict__ Xb)
{
    size_t i = ((size_t)blockIdx.x * 256 + threadIdx.x) * 8;
    float4 v0 = *(const float4*)(X + i);
    float4 v1 = *(const float4*)(X + i + 4);
    u16x8 o;
    o[0] = f2bf(v0.x); o[1] = f2bf(v0.y); o[2] = f2bf(v0.z); o[3] = f2bf(v0.w);
    o[4] = f2bf(v1.x); o[5] = f2bf(v1.y); o[6] = f2bf(v1.z); o[7] = f2bf(v1.w);
    *(u16x8*)(Xb + i) = o;
}

// ---------------------------------------------------------------------------
// W [K][N] fp32 -> Wt [N][K] bf16 transposed; Wq pre-scaled by QSCALE.
// ---------------------------------------------------------------------------
__global__ __launch_bounds__(256)
void convert_wt(const float* __restrict__ Wq, const float* __restrict__ Wk,
                const float* __restrict__ Wv, u16* __restrict__ Wt)
{
    const int z = blockIdx.z;
    const float* W = (z == 0) ? Wq : (z == 1) ? Wk : Wv;
    const float sc = (z == 0) ? QSCALE : 1.0f;
    u16* Wo = Wt + (size_t)z * CD * CD;

    __shared__ u16 T[64][72];
    const int k0 = blockIdx.x << 6;
    const int n0 = blockIdx.y << 6;
    const int tid = threadIdx.x;

    #pragma unroll
    for (int it = 0; it < 4; ++it) {
        int r = (tid >> 4) + (it << 4);
        int c = (tid & 15) << 2;
        float4 v = *(const float4*)(W + (size_t)(k0 + r) * CD + n0 + c);
        T[c + 0][r] = f2bf(v.x * sc);
        T[c + 1][r] = f2bf(v.y * sc);
        T[c + 2][r] = f2bf(v.z * sc);
        T[c + 3][r] = f2bf(v.w * sc);
    }
    __syncthreads();
    #pragma unroll
    for (int it = 0; it < 2; ++it) {
        int cc = tid + (it << 8);
        int n  = cc >> 3;
        int ch = (cc & 7) << 3;
        *(uint4*)(Wo + (size_t)(n0 + n) * CD + k0 + ch) = *(const uint4*)&T[n][ch];
    }
}

// ---------------------------------------------------------------------------
// QKV GEMM, bf16 MFMA 16x16x32.  128x128 tile, BK=64, global_load_lds staging
// with 8-slot XOR swizzle (stored slot = chunk ^ (row&7)); fragment
// ds_read_b128 at slot (kk*4+quad)^(l15&7) is uniformly 2-way (free).
// ---------------------------------------------------------------------------
__global__ __launch_bounds__(256, 3)
void qkv_gemm_mfma(const u16* __restrict__ Xb, const u16* __restrict__ Wt,
                   const float* __restrict__ bq, const float* __restrict__ bk,
                   const float* __restrict__ bv,
                   u16* __restrict__ Qb, u16* __restrict__ Kb,
                   u16* __restrict__ Vt)
{
    const int z = blockIdx.z;
    const u16* W = Wt + (size_t)z * CD * CD;
    const float* bias = (z == 0) ? bq : (z == 1) ? bk : bv;
    const float bscale = (z == 0) ? QSCALE : 1.0f;

    __shared__ u16 smem[16384];         // As [128][64] + Bs [128][64] = 32 KB
    u16* As = smem;
    u16* Bs = smem + 8192;

    const int tid  = threadIdx.x;
    const int w    = tid >> 6;
    const int l    = tid & 63;
    const int l15  = l & 15;
    const int quad = l >> 4;
    const int wm   = w >> 1;
    const int wn   = w & 1;

    const int row0 = blockIdx.x << 7;
    const int n0   = blockIdx.y << 7;

    f32x4 acc[4][4];
    #pragma unroll
    for (int mi = 0; mi < 4; ++mi)
        #pragma unroll
        for (int nt = 0; nt < 4; ++nt)
            acc[mi][nt] = (f32x4){0.f, 0.f, 0.f, 0.f};

    const u16* Ag = Xb + (size_t)row0 * CD;
    const u16* Bg = W  + (size_t)n0   * CD;
    const int lr8 = l >> 3;                 // 0..7: row within 8-row group
    const int ls  = l & 7;                  // stored slot
    const int lg  = (ls ^ lr8) << 3;        // global chunk offset (u16)
    const int q7  = l15 & 7;

    for (int k0 = 0; k0 < CD; k0 += 64) {
        __syncthreads();
        #pragma unroll
        for (int i = 0; i < 4; ++i) {
            int r = w * 32 + 8 * i + lr8;
            load_lds16(Ag + (size_t)r * CD + k0 + lg, As + (size_t)(w * 32 + 8 * i) * 64);
            load_lds16(Bg + (size_t)r * CD + k0 + lg, Bs + (size_t)(w * 32 + 8 * i) * 64);
        }
        __syncthreads();

        #pragma unroll
        for (int kk = 0; kk < 2; ++kk) {
            bf16x8 af[4], bfr[4];
            #pragma unroll
            for (int mi = 0; mi < 4; ++mi)
                af[mi] = *(const bf16x8*)
                    &As[(wm * 64 + mi * 16 + l15) * 64 + (((kk * 4 + quad) ^ q7) << 3)];
            #pragma unroll
            for (int nt = 0; nt < 4; ++nt)
                bfr[nt] = *(const bf16x8*)
                    &Bs[(wn * 64 + nt * 16 + l15) * 64 + (((kk * 4 + quad) ^ q7) << 3)];
            #pragma unroll
            for (int mi = 0; mi < 4; ++mi)
                #pragma unroll
                for (int nt = 0; nt < 4; ++nt)
                    acc[mi][nt] = __builtin_amdgcn_mfma_f32_16x16x32_bf16(
                        af[mi], bfr[nt], acc[mi][nt], 0, 0, 0);
        }
    }

    __syncthreads();   // K-loop LDS reads done; smem reusable

    if (z < 2) {
        u16* Og = (z == 0) ? Qb : Kb;
        float bb[4];
        #pragma unroll
        for (int nt = 0; nt < 4; ++nt)
            bb[nt] = bias[n0 + wn * 64 + nt * 16 + l15] * bscale;

        u16 (*Ct)[136] = (u16(*)[136])smem;
        #pragma unroll
        for (int mh = 0; mh < 2; ++mh) {
            if (wm == mh) {
                #pragma unroll
                for (int nt = 0; nt < 4; ++nt)
                    #pragma unroll
                    for (int mi = 0; mi < 4; ++mi)
                        #pragma unroll
                        for (int r = 0; r < 4; ++r)
                            Ct[mi * 16 + quad * 4 + r][wn * 64 + nt * 16 + l15] =
                                f2bf(acc[mi][nt][r] + bb[nt]);
            }
            __syncthreads();
            #pragma unroll
            for (int it = 0; it < 4; ++it) {
                int c  = tid + (it << 8);
                int rl = c >> 4;
                int ck = c & 15;
                uint4 d = *(const uint4*)&Ct[rl][ck * 8];
                int gcol = n0 + ck * 8;
                int h = gcol >> 6, hd = gcol & 63;
                int m = row0 + mh * 64 + rl;
                int b = m >> 11, s = m & (CS - 1);
                *(uint4*)(Og + ((size_t)(b * CH + h) * CS + s) * CHD + hd) = d;
            }
            __syncthreads();
        }
    } else {
        u16 (*Ct)[136] = (u16(*)[136])smem;
        #pragma unroll
        for (int nh = 0; nh < 2; ++nh) {
            if (wn == nh) {
                #pragma unroll
                for (int nt = 0; nt < 4; ++nt) {
                    int col = n0 + nh * 64 + nt * 16 + l15;
                    float bb = bias[col];
                    #pragma unroll
                    for (int mi = 0; mi < 4; ++mi)
                        #pragma unroll
                        for (int r = 0; r < 4; ++r) {
                            int ml = wm * 64 + mi * 16 + quad * 4 + r;
                            Ct[nt * 16 + l15][ml] = f2bf(acc[mi][nt][r] + bb);
                        }
                }
            }
            __syncthreads();
            #pragma unroll
            for (int it = 0; it < 4; ++it) {
                int c   = tid + (it << 8);
                int dvl = c >> 4;
                int ch  = c & 15;
                uint4 vdat = *(const uint4*)&Ct[dvl][ch * 8];
                int col = n0 + nh * 64 + dvl;
                int h   = col >> 6;
                int dv  = col & 63;
                int m0  = row0 + ch * 8;
                int b   = m0 >> 11;
                int s0  = m0 & (CS - 1);
                *(uint4*)(Vt + (((size_t)(b * CH + h)) * CHD + dv) * CS + s0) = vdat;
            }
            __syncthreads();
        }
    }
}

// ---------------------------------------------------------------------------
// Flash attention v6: LDS-staged K/V via global_load_lds (coalesced DMA,
// shared across all 4 waves), double-buffered with ONE barrier per k-tile
// (m97 structure).  q-block 128 (wave w owns q [w*32,w*32+32), nq=2).
// Static-bound softmax (p = exp2(S + mask*log2e - B), no running max);
// C-init = mask; P via wave-private XOR-swizzled LDS; 2 shfls per kernel.
// K/V rows staged with 8-slot XOR swizzle -> fragment ds_read_b128 2-way.
// ---------------------------------------------------------------------------
__global__ __launch_bounds__(256, 2)
void attn_mfma(const u16* __restrict__ Qg, const u16* __restrict__ Kg,
               const u16* __restrict__ Vtg, const float* __restrict__ mask,
               float* __restrict__ out)
{
    __shared__ float msk[CS];           // 8 KB: mask*log2e - B
    __shared__ u16   Kst[2][64 * 64];   // 16 KB: K tiles [key][d], swizzled
    __shared__ u16   Vst[2][64 * 64];   // 16 KB: V^T tiles [dv][key], swizzled
    __shared__ u16   Pl[4][32 * 64];    // 16 KB: per-wave P
    __shared__ float abuf[4][32];       // l broadcast

    const int q0  = blockIdx.x << 7;
    const int bh  = blockIdx.y;
    const int b   = bh >> 4;
    const int h   = bh & 15;
    const int tid = threadIdx.x;
    const int w    = tid >> 6;
    const int l    = tid & 63;
    const int l15  = l & 15;
    const int quad = l >> 4;
    const int q7   = l15 & 7;
    const int lr8  = l >> 3;            // DMA: row within 8-row group
    const int lg   = ((l & 7) ^ lr8) << 3;  // DMA: swizzled global chunk (u16)

    const u16* Qp = Qg  + (size_t)bh * CS * CHD;
    const u16* Kp = Kg  + (size_t)bh * CS * CHD;
    const u16* Vp = Vtg + (size_t)bh * CHD * CS;
    const float* mrow = mask + (size_t)b * CS;

    // stage mask (whole row, log2 domain, bound folded in)
    {
        int i = tid * 8;
        float4 a = *(const float4*)(mrow + i);
        float4 c = *(const float4*)(mrow + i + 4);
        msk[i + 0] = a.x * LOG2E - BLOG; msk[i + 1] = a.y * LOG2E - BLOG;
        msk[i + 2] = a.z * LOG2E - BLOG; msk[i + 3] = a.w * LOG2E - BLOG;
        msk[i + 4] = c.x * LOG2E - BLOG; msk[i + 5] = c.y * LOG2E - BLOG;
        msk[i + 6] = c.z * LOG2E - BLOG; msk[i + 7] = c.w * LOG2E - BLOG;
    }

    // DMA stage of one 64-key tile into buffer bb (wave w covers 16 K-rows
    // and 16 V^T-rows; 8 rows per glds instruction)
    auto stage = [&](int k0, int bb) {
        #pragma unroll
        for (int i = 0; i < 2; ++i) {
            int rl = w * 16 + 8 * i;
            load_lds16(Kp + (size_t)(k0 + rl + lr8) * CHD + lg, &Kst[bb][rl * 64]);
            load_lds16(Vp + (size_t)(rl + lr8) * CS + k0 + lg,  &Vst[bb][rl * 64]);
        }
    };

    stage(0, 0);

    // Q B-fragments in registers for the whole loop
    bf16x8 qf[2][2];
    #pragma unroll
    for (int nq = 0; nq < 2; ++nq)
        #pragma unroll
        for (int hh = 0; hh < 2; ++hh)
            qf[nq][hh] = *(const bf16x8*)(
                Qp + (size_t)(q0 + w * 32 + nq * 16 + l15) * CHD + hh * 32 + quad * 8);

    u16* Pw = &Pl[w][0];
    float lsum[2] = {0.f, 0.f};
    f32x4 O[2][4];
    #pragma unroll
    for (int nq = 0; nq < 2; ++nq)
        #pragma unroll
        for (int dt = 0; dt < 4; ++dt)
            O[nq][dt] = (f32x4){0.f, 0.f, 0.f, 0.f};

    for (int kt = 0; kt < CS / 64; ++kt) {
        const int k0 = kt << 6;
        const int cc = kt & 1;
        __syncthreads();                 // tile kt staged+visible; prev reads done
        if (kt + 1 < CS / 64)
            stage(k0 + 64, cc ^ 1);      // DMA next tile while computing this one

        // K A-fragments from LDS (swizzled, 2-way)
        bf16x8 kf[4][2];
        #pragma unroll
        for (int mt = 0; mt < 4; ++mt)
            #pragma unroll
            for (int hh = 0; hh < 2; ++hh)
                kf[mt][hh] = *(const bf16x8*)
                    &Kst[cc][(mt * 16 + l15) * 64 + (((hh * 4 + quad) ^ q7) << 3)];

        // S^T + exp2 + pack (nq-sequenced)
        #pragma unroll
        for (int nq = 0; nq < 2; ++nq) {
            f32x4 st[4];
            #pragma unroll
            for (int mt = 0; mt < 4; ++mt) {
                f32x4 c0 = *(const f32x4*)&msk[k0 + mt * 16 + quad * 4];
                c0 = __builtin_amdgcn_mfma_f32_16x16x32_bf16(kf[mt][0], qf[nq][0], c0, 0, 0, 0);
                st[mt] = __builtin_amdgcn_mfma_f32_16x16x32_bf16(kf[mt][1], qf[nq][1], c0, 0, 0, 0);
            }
            float rs = lsum[nq];
            #pragma unroll
            for (int mt = 0; mt < 4; ++mt) {
                #pragma unroll
                for (int r = 0; r < 4; ++r) {
                    st[mt][r] = exp2f(st[mt][r]);
                    rs += st[mt][r];
                }
                int g = 2 * mt + (quad >> 1);
                int addr = (nq * 16 + l15) * 64 + ((g ^ q7) << 3) + ((quad & 1) << 2);
                uint2 d;
                d.x = pack2bf(st[mt][0], st[mt][1]);
                d.y = pack2bf(st[mt][2], st[mt][3]);
                *(uint2*)&Pw[addr] = d;
            }
            lsum[nq] = rs;
        }

        // P A-fragments back (wave-private)
        bf16x8 pf[2][2];
        #pragma unroll
        for (int nq = 0; nq < 2; ++nq)
            #pragma unroll
            for (int hh = 0; hh < 2; ++hh)
                pf[nq][hh] = *(const bf16x8*)
                    &Pw[(nq * 16 + l15) * 64 + (((hh * 4 + quad) ^ q7) << 3)];

        // V^T B-fragments from LDS
        bf16x8 vf[4][2];
        #pragma unroll
        for (int dt = 0; dt < 4; ++dt)
            #pragma unroll
            for (int hh = 0; hh < 2; ++hh)
                vf[dt][hh] = *(const bf16x8*)
                    &Vst[cc][(dt * 16 + l15) * 64 + (((hh * 4 + quad) ^ q7) << 3)];

        // O += P.V  (no rescale: static bound)
        #pragma unroll
        for (int nq = 0; nq < 2; ++nq)
            #pragma unroll
            for (int dt = 0; dt < 4; ++dt) {
                O[nq][dt] = __builtin_amdgcn_mfma_f32_16x16x32_bf16(
                    pf[nq][0], vf[dt][0], O[nq][dt], 0, 0, 0);
                O[nq][dt] = __builtin_amdgcn_mfma_f32_16x16x32_bf16(
                    pf[nq][1], vf[dt][1], O[nq][dt], 0, 0, 0);
            }
    }

    // ---- l reduce across quads + broadcast to C-row domain ----
    #pragma unroll
    for (int nq = 0; nq < 2; ++nq) {
        lsum[nq] += __shfl_xor(lsum[nq], 16);
        lsum[nq] += __shfl_xor(lsum[nq], 32);
    }
    if (quad == 0) {
        abuf[w][l15]      = lsum[0];
        abuf[w][16 + l15] = lsum[1];
    }
    __builtin_amdgcn_s_waitcnt(0);   // wave-private LDS visibility

    #pragma unroll
    for (int nq = 0; nq < 2; ++nq) {
        f32x4 lo = *(const f32x4*)&abuf[w][nq * 16 + quad * 4];
        #pragma unroll
        for (int r = 0; r < 4; ++r) {
            float inv = 1.0f / lo[r];
            int q = q0 + w * 32 + nq * 16 + quad * 4 + r;
            float* orow = out + ((size_t)b * CS + q) * CD + h * CHD;
            #pragma unroll
            for (int dt = 0; dt < 4; ++dt)
                orow[dt * 16 + l15] = O[nq][dt][r] * inv;
        }
    }
}

// ---------------------------------------------------------------------------
extern "C" void kernel_launch(void* const* d_in, const int* in_sizes, int n_in,
                              void* d_out, int out_size, void* d_ws, size_t ws_size,
                              hipStream_t stream)
{
    const float* X    = (const float*)d_in[0];
    const float* mask = (const float*)d_in[1];
    const float* Wq   = (const float*)d_in[2];
    const float* bq   = (const float*)d_in[3];
    const float* Wk   = (const float*)d_in[4];
    const float* bk   = (const float*)d_in[5];
    const float* Wv   = (const float*)d_in[6];
    const float* bv   = (const float*)d_in[7];
    float* out = (float*)d_out;

    char* ws = (char*)d_ws;
    u16* Xb = (u16*)(ws);
    u16* Wt = (u16*)(ws + ((size_t)8  << 20));
    u16* Qb = (u16*)(ws + ((size_t)14 << 20));
    u16* Kb = (u16*)(ws + ((size_t)22 << 20));
    u16* Vt = (u16*)(ws + ((size_t)30 << 20));

    convert_x<<<CM * CD / (256 * 8), 256, 0, stream>>>(X, Xb);
    convert_wt<<<dim3(16, 16, 3), 256, 0, stream>>>(Wq, Wk, Wv, Wt);
    qkv_gemm_mfma<<<dim3(CM / 128, CD / 128, 3), 256, 0, stream>>>(
        Xb, Wt, bq, bk, bv, Qb, Kb, Vt);
    attn_mfma<<<dim3(CS / 128, CB * CH), 256, 0, stream>>>(Qb, Kb, Vt, mask, out);
}